// Round 3
// baseline (9624.164 us; speedup 1.0000x reference)
//
#include <hip/hip_runtime.h>
#include <hip/hip_bf16.h>
#include <math.h>

typedef __hip_bfloat16 bf16;
typedef float v2f __attribute__((ext_vector_type(2)));

__device__ __forceinline__ float b2f(bf16 v) { return __bfloat162float(v); }
__device__ __forceinline__ float unpk_lo(unsigned u) { return __uint_as_float(u << 16); }
__device__ __forceinline__ float unpk_hi(unsigned u) { return __uint_as_float(u & 0xffff0000u); }
__device__ __forceinline__ v2f unpk2(unsigned u) {
    v2f r; r.x = __uint_as_float(u << 16); r.y = __uint_as_float(u & 0xffff0000u); return r;
}
__device__ __forceinline__ unsigned pk2(float a, float b) {
    unsigned ua = __float_as_uint(a);
    unsigned ub = __float_as_uint(b);
    ua = (ua + 0x7fffu + ((ua >> 16) & 1u)) >> 16;   // RNE to bf16
    ub = (ub + 0x7fffu + ((ub >> 16) & 1u)) >> 16;
    return ua | (ub << 16);
}
__device__ __forceinline__ float gelu_exact(float x) {
    return 0.5f * x * (1.f + erff(x * 0.70710678118654752440f));
}

// ---------------------------------------------------------------------------
// Kernel 1: ctx = LN(context^T over EC=256) @ ctxp_w + ctxp_b -> (B,HW,64) bf16
// ---------------------------------------------------------------------------
__global__ __launch_bounds__(256) void k_ctx(const float* __restrict__ ctx,
                                             const float* __restrict__ g,
                                             const float* __restrict__ bb,
                                             const float* __restrict__ w,
                                             const float* __restrict__ pb,
                                             bf16* __restrict__ outp) {
    __shared__ unsigned tile[256][32];
    __shared__ float redS[8][64];
    __shared__ float redQ[8][64];
    __shared__ float s_mu[64], s_rs[64];
    const int t  = threadIdx.x;
    const int tx = t & 31;
    const int ty = t >> 5;
    const int b   = blockIdx.x >> 6;
    const int hw0 = (blockIdx.x & 63) << 6;
    const float* cbase = ctx + ((size_t)b * 256) * 4096 + hw0 + 2 * tx;
    float sa = 0.f, qa = 0.f, sb = 0.f, qb2 = 0.f;
    for (int e = ty; e < 256; e += 8) {
        float2 v = *(const float2*)(cbase + (size_t)e * 4096);
        tile[e][tx] = pk2(v.x, v.y);
        sa += v.x; qa += v.x * v.x;
        sb += v.y; qb2 += v.y * v.y;
    }
    redS[ty][2 * tx] = sa;  redS[ty][2 * tx + 1] = sb;
    redQ[ty][2 * tx] = qa;  redQ[ty][2 * tx + 1] = qb2;
    __syncthreads();
    if (t < 64) {
        float st = 0.f, qt = 0.f;
#pragma unroll
        for (int k = 0; k < 8; ++k) { st += redS[k][t]; qt += redQ[k][t]; }
        float mu = st * (1.f / 256.f);
        float var = qt * (1.f / 256.f) - mu * mu;
        s_mu[t] = mu;
        s_rs[t] = rsqrtf(var + 1e-5f);
    }
    __syncthreads();
    {
        float mu0 = s_mu[2 * tx], mu1 = s_mu[2 * tx + 1];
        float rs0 = s_rs[2 * tx], rs1 = s_rs[2 * tx + 1];
        for (int e = ty; e < 256; e += 8) {
            unsigned u = tile[e][tx];
            float ge = g[e], be = bb[e];
            float a0 = (unpk_lo(u) - mu0) * rs0 * ge + be;
            float a1 = (unpk_hi(u) - mu1) * rs1 * ge + be;
            tile[e][tx] = pk2(a0, a1);
        }
    }
    __syncthreads();
    const int tx2 = t & 63;
    const int ty2 = t >> 6;
    v2f acc[8];
#pragma unroll
    for (int q = 0; q < 8; ++q) { acc[q].x = pb[ty2 * 16 + 2 * q]; acc[q].y = pb[ty2 * 16 + 2 * q + 1]; }
    for (int e = 0; e < 256; ++e) {
        unsigned u = tile[e][tx2 >> 1];
        float a = (tx2 & 1) ? unpk_hi(u) : unpk_lo(u);
        const float4* wv = (const float4*)(w + e * 64 + ty2 * 16);
        float4 w0 = wv[0], w1 = wv[1], w2v = wv[2], w3 = wv[3];
        acc[0] += (v2f){w0.x, w0.y} * a;   acc[1] += (v2f){w0.z, w0.w} * a;
        acc[2] += (v2f){w1.x, w1.y} * a;   acc[3] += (v2f){w1.z, w1.w} * a;
        acc[4] += (v2f){w2v.x, w2v.y} * a; acc[5] += (v2f){w2v.z, w2v.w} * a;
        acc[6] += (v2f){w3.x, w3.y} * a;   acc[7] += (v2f){w3.z, w3.w} * a;
    }
    unsigned* orow = (unsigned*)(outp + ((size_t)b * 4096 + hw0 + tx2) * 64 + ty2 * 16);
    uint4 o0, o1;
    o0.x = pk2(acc[0].x, acc[0].y); o0.y = pk2(acc[1].x, acc[1].y);
    o0.z = pk2(acc[2].x, acc[2].y); o0.w = pk2(acc[3].x, acc[3].y);
    o1.x = pk2(acc[4].x, acc[4].y); o1.y = pk2(acc[5].x, acc[5].y);
    o1.z = pk2(acc[6].x, acc[6].y); o1.w = pk2(acc[7].x, acc[7].y);
    ((uint4*)orow)[0] = o0;
    ((uint4*)orow)[1] = o1;
}

// ---------------------------------------------------------------------------
// Kernel 2: LN(concat(x,ctx),192) -> q,k ; LN(x,128) -> v. 16 rows/block.
// Compute: thread = 4 cols x 2 rows, v_pk_fma_f32 via v2f. grid 4096, blk 256.
// ---------------------------------------------------------------------------
__global__ __launch_bounds__(256) void k_qkv(const float* __restrict__ x,
                                             const bf16* __restrict__ ctxp,
                                             const float* __restrict__ n1g, const float* __restrict__ n1b,
                                             const float* __restrict__ nvg, const float* __restrict__ nvb,
                                             const float* __restrict__ qw, const float* __restrict__ qb,
                                             const float* __restrict__ kw, const float* __restrict__ kb,
                                             const float* __restrict__ vw, const float* __restrict__ vb,
                                             bf16* __restrict__ qo, bf16* __restrict__ ko,
                                             bf16* __restrict__ vo) {
    __shared__ float qkn[16][192];
    __shared__ float vvn[16][128];
    const int t  = threadIdx.x;
    const int r  = t >> 4;
    const int li = t & 15;
    const int row0 = blockIdx.x * 16;
    {
        const float* xr = x + (size_t)(row0 + r) * 128;
        const bf16*  cr = ctxp + (size_t)(row0 + r) * 64;
        float xv[8], cv[4];
        float s1 = 0.f, s2 = 0.f;
#pragma unroll
        for (int k = 0; k < 8; ++k) { float v = xr[li + 16 * k]; xv[k] = v; s1 += v; s2 += v * v; }
        float t1 = s1, t2 = s2;
#pragma unroll
        for (int k = 0; k < 4; ++k) { float v = b2f(cr[li + 16 * k]); cv[k] = v; s1 += v; s2 += v * v; }
#pragma unroll
        for (int o = 1; o < 16; o <<= 1) {
            s1 += __shfl_xor(s1, o); s2 += __shfl_xor(s2, o);
            t1 += __shfl_xor(t1, o); t2 += __shfl_xor(t2, o);
        }
        float mu  = s1 * (1.f / 192.f);
        float rs  = rsqrtf(s2 * (1.f / 192.f) - mu * mu + 1e-5f);
        float muv = t1 * (1.f / 128.f);
        float rsv = rsqrtf(t2 * (1.f / 128.f) - muv * muv + 1e-5f);
#pragma unroll
        for (int k = 0; k < 8; ++k) {
            int c = li + 16 * k;
            qkn[r][c] = (xv[k] - mu) * rs * n1g[c] + n1b[c];
            vvn[r][c] = (xv[k] - muv) * rsv * nvg[c] + nvb[c];
        }
#pragma unroll
        for (int k = 0; k < 4; ++k) {
            int c = 128 + li + 16 * k;
            qkn[r][c] = (cv[k] - mu) * rs * n1g[c] + n1b[c];
        }
    }
    __syncthreads();
    const int cg = t & 31;
    const int rg = t >> 5;
    const int c0 = cg * 4;
    const int r0 = rg * 2;
    const int head = c0 >> 4;
    const int d    = c0 & 15;
    const int rowA = row0 + r0, rowB = rowA + 1;
    const int bA = rowA >> 12, hwA = rowA & 4095;
    const int bB = rowB >> 12, hwB = rowB & 4095;
    const size_t oiA = (((size_t)bA * 8 + head) * 4096 + hwA) * 16 + d;
    const size_t oiB = (((size_t)bB * 8 + head) * 4096 + hwB) * 16 + d;
    // ---- q ----
    {
        float4 bv = *(const float4*)&qb[c0];
        v2f a00 = {bv.x, bv.y}, a01 = {bv.z, bv.w};
        v2f a10 = a00, a11 = a01;
        for (int e = 0; e < 192; e += 4) {
            float4 n0 = *(const float4*)&qkn[r0][e];
            float4 n1 = *(const float4*)&qkn[r0 + 1][e];
            float na0[4] = {n0.x, n0.y, n0.z, n0.w};
            float na1[4] = {n1.x, n1.y, n1.z, n1.w};
#pragma unroll
            for (int ei = 0; ei < 4; ++ei) {
                float4 w = *(const float4*)&qw[(e + ei) * 128 + c0];
                v2f wlo = {w.x, w.y}, whi = {w.z, w.w};
                a00 += wlo * na0[ei]; a01 += whi * na0[ei];
                a10 += wlo * na1[ei]; a11 += whi * na1[ei];
            }
        }
        *(uint2*)(qo + oiA) = (uint2){pk2(a00.x * 0.25f, a00.y * 0.25f), pk2(a01.x * 0.25f, a01.y * 0.25f)};
        *(uint2*)(qo + oiB) = (uint2){pk2(a10.x * 0.25f, a10.y * 0.25f), pk2(a11.x * 0.25f, a11.y * 0.25f)};
    }
    // ---- k ----
    {
        float4 bv = *(const float4*)&kb[c0];
        v2f a00 = {bv.x, bv.y}, a01 = {bv.z, bv.w};
        v2f a10 = a00, a11 = a01;
        for (int e = 0; e < 192; e += 4) {
            float4 n0 = *(const float4*)&qkn[r0][e];
            float4 n1 = *(const float4*)&qkn[r0 + 1][e];
            float na0[4] = {n0.x, n0.y, n0.z, n0.w};
            float na1[4] = {n1.x, n1.y, n1.z, n1.w};
#pragma unroll
            for (int ei = 0; ei < 4; ++ei) {
                float4 w = *(const float4*)&kw[(e + ei) * 128 + c0];
                v2f wlo = {w.x, w.y}, whi = {w.z, w.w};
                a00 += wlo * na0[ei]; a01 += whi * na0[ei];
                a10 += wlo * na1[ei]; a11 += whi * na1[ei];
            }
        }
        *(uint2*)(ko + oiA) = (uint2){pk2(a00.x, a00.y), pk2(a01.x, a01.y)};
        *(uint2*)(ko + oiB) = (uint2){pk2(a10.x, a10.y), pk2(a11.x, a11.y)};
    }
    // ---- v ----
    {
        float4 bv = *(const float4*)&vb[c0];
        v2f a00 = {bv.x, bv.y}, a01 = {bv.z, bv.w};
        v2f a10 = a00, a11 = a01;
        for (int e = 0; e < 128; e += 4) {
            float4 n0 = *(const float4*)&vvn[r0][e];
            float4 n1 = *(const float4*)&vvn[r0 + 1][e];
            float na0[4] = {n0.x, n0.y, n0.z, n0.w};
            float na1[4] = {n1.x, n1.y, n1.z, n1.w};
#pragma unroll
            for (int ei = 0; ei < 4; ++ei) {
                float4 w = *(const float4*)&vw[(e + ei) * 128 + c0];
                v2f wlo = {w.x, w.y}, whi = {w.z, w.w};
                a00 += wlo * na0[ei]; a01 += whi * na0[ei];
                a10 += wlo * na1[ei]; a11 += whi * na1[ei];
            }
        }
        *(uint2*)(vo + oiA) = (uint2){pk2(a00.x, a00.y), pk2(a01.x, a01.y)};
        *(uint2*)(vo + oiB) = (uint2){pk2(a10.x, a10.y), pk2(a11.x, a11.y)};
    }
}

// ---------------------------------------------------------------------------
// Kernel 3: neighborhood attention, K=11. 256-thread block = 4 waves = 4
// consecutive i rows sharing one staged k/v window (<=14 rows). Fixed-max
// softmax (scores bounded, exp-direct is exact after normalization).
// LDS stride 10 uints -> 8B aligned ds_read_b64, 2-way bank alias (free).
// grid 2048 (= B*h*(H/4)).
// ---------------------------------------------------------------------------
__global__ __launch_bounds__(256) void k_attn(const bf16* __restrict__ qws,
                                              const bf16* __restrict__ kws,
                                              const bf16* __restrict__ vws,
                                              const float* __restrict__ rpb,
                                              bf16* __restrict__ ows) {
    __shared__ unsigned kt[14][64][10];
    __shared__ unsigned vt[14][64][10];
    const int tid  = threadIdx.x;
    const int bh   = blockIdx.x >> 4;
    const int i0   = (blockIdx.x & 15) << 2;
    const int head = bh & 7;
    int start_min = i0 - 5; if (start_min < 0) start_min = 0; if (start_min > 53) start_min = 53;
    const unsigned* ku = (const unsigned*)kws;
    const unsigned* vu = (const unsigned*)vws;
    const size_t gbase = ((size_t)bh * 4096 + (size_t)start_min * 64) * 8;
    for (int idx = tid; idx < 7168; idx += 256) {
        int a = idx >> 9; int rem = idx & 511;
        int col = rem >> 3; int d2 = rem & 7;
        if (start_min + a < 64) {
            kt[a][col][d2] = ku[gbase + (size_t)a * 512 + rem];
            vt[a][col][d2] = vu[gbase + (size_t)a * 512 + rem];
        }
    }
    __syncthreads();
    const int wv = tid >> 6;
    const int j  = tid & 63;
    const int i  = i0 + wv;
    int start_i = i - 5; if (start_i < 0) start_i = 0; if (start_i > 53) start_i = 53;
    const int off = start_i - start_min;
    v2f qv[8];
    {
        const uint4* qp = (const uint4*)(qws + ((size_t)bh * 4096 + i * 64 + j) * 16);
        uint4 q0 = qp[0], q1 = qp[1];
        qv[0] = unpk2(q0.x); qv[1] = unpk2(q0.y); qv[2] = unpk2(q0.z); qv[3] = unpk2(q0.w);
        qv[4] = unpk2(q1.x); qv[5] = unpk2(q1.y); qv[6] = unpk2(q1.z); qv[7] = unpk2(q1.w);
    }
    int start_j = j - 5; if (start_j < 0) start_j = 0; if (start_j > 53) start_j = 53;
    float l = 0.f;
    v2f acc[8];
#pragma unroll
    for (int d = 0; d < 8; ++d) acc[d] = (v2f){0.f, 0.f};
    const float* rpb_h = rpb + head * 441 + (start_j - j + 10);
    for (int a = 0; a < 11; ++a) {
        const int r = off + a;
        const float* rb = rpb_h + (start_i + a - i + 10) * 21;
#pragma unroll
        for (int c = 0; c < 11; ++c) {
            const int jj = start_j + c;
            const unsigned* kp = kt[r][jj];
            v2f dv = qv[0] * unpk2(kp[0]);
            dv += qv[1] * unpk2(kp[1]);
            dv += qv[2] * unpk2(kp[2]);
            dv += qv[3] * unpk2(kp[3]);
            dv += qv[4] * unpk2(kp[4]);
            dv += qv[5] * unpk2(kp[5]);
            dv += qv[6] * unpk2(kp[6]);
            dv += qv[7] * unpk2(kp[7]);
            float s = rb[c] + dv.x + dv.y;
            float p = __expf(s);
            l += p;
            const unsigned* vp = vt[r][jj];
#pragma unroll
            for (int d2 = 0; d2 < 8; ++d2)
                acc[d2] += unpk2(vp[d2]) * p;
        }
    }
    float inv = 1.f / l;
    int b = bh >> 3;
    unsigned* op = (unsigned*)ows + ((size_t)b * 4096 + i * 64 + j) * 64 + head * 8;
#pragma unroll
    for (int d2 = 0; d2 < 8; ++d2)
        op[d2] = pk2(acc[d2].x * inv, acc[d2].y * inv);
}

// ---------------------------------------------------------------------------
// Kernel 4: y = x + concat(o, x) @ proj_w + proj_b -> fp32 ws.
// 16 rows/block; thread = 4 cols x 2 rows, pk_fma. grid 4096, blk 256.
// ---------------------------------------------------------------------------
__global__ __launch_bounds__(256) void k_proj(const float* __restrict__ x,
                                              const bf16* __restrict__ ows,
                                              const float* __restrict__ pw,
                                              const float* __restrict__ pb,
                                              float* __restrict__ yws) {
    __shared__ float inb[16][256];
    const int t = threadIdx.x;
    const size_t row0 = (size_t)blockIdx.x * 16;
    for (int idx = t; idx < 2048; idx += 256) {
        int r = idx >> 7, c2 = idx & 127;
        inb[r][c2] = b2f(ows[(row0 + r) * 128 + c2]);
    }
    for (int idx = t; idx < 2048; idx += 256) {
        int r = idx >> 7, c2 = idx & 127;
        inb[r][128 + c2] = x[(row0 + r) * 128 + c2];
    }
    __syncthreads();
    const int cg = t & 31, rg = t >> 5;
    const int c0 = cg * 4, r0 = rg * 2;
    float4 bv = *(const float4*)&pb[c0];
    v2f a00 = {bv.x, bv.y}, a01 = {bv.z, bv.w};
    v2f a10 = a00, a11 = a01;
    for (int e = 0; e < 256; e += 4) {
        float4 n0 = *(const float4*)&inb[r0][e];
        float4 n1 = *(const float4*)&inb[r0 + 1][e];
        float na0[4] = {n0.x, n0.y, n0.z, n0.w};
        float na1[4] = {n1.x, n1.y, n1.z, n1.w};
#pragma unroll
        for (int ei = 0; ei < 4; ++ei) {
            float4 w = *(const float4*)&pw[(e + ei) * 128 + c0];
            v2f wlo = {w.x, w.y}, whi = {w.z, w.w};
            a00 += wlo * na0[ei]; a01 += whi * na0[ei];
            a10 += wlo * na1[ei]; a11 += whi * na1[ei];
        }
    }
    float4 x0 = *(const float4*)&inb[r0][128 + c0];
    float4 x1 = *(const float4*)&inb[r0 + 1][128 + c0];
    float4 o0 = {x0.x + a00.x, x0.y + a00.y, x0.z + a01.x, x0.w + a01.y};
    float4 o1 = {x1.x + a10.x, x1.y + a10.y, x1.z + a11.x, x1.w + a11.y};
    *(float4*)&yws[(row0 + r0) * 128 + c0]     = o0;
    *(float4*)&yws[(row0 + r0 + 1) * 128 + c0] = o1;
}

// ---------------------------------------------------------------------------
// Kernel 5: ffn = gelu(LN(y)@f1+b1)@f2+b2; out = fp32(y + ffn).
// 16 rows/block; f1: thread = 4 cols x 8 rows; f2: 4 cols x 2 rows. pk_fma.
// ---------------------------------------------------------------------------
__global__ __launch_bounds__(256) void k_ffn(const float* __restrict__ yws,
                                             const float* __restrict__ g, const float* __restrict__ bb,
                                             const float* __restrict__ w1, const float* __restrict__ b1,
                                             const float* __restrict__ w2, const float* __restrict__ b2,
                                             float* __restrict__ outp) {
    __shared__ float nrm[16][128];
    __shared__ float hb[16][512];
    __shared__ float ybuf[16][128];
    const int t  = threadIdx.x;
    const int r  = t >> 4;
    const int li = t & 15;
    const size_t row0 = (size_t)blockIdx.x * 16;
    {
        const float* yr = yws + (row0 + r) * 128;
        float v[8];
        float s1 = 0.f, s2 = 0.f;
#pragma unroll
        for (int k = 0; k < 8; ++k) { float vv = yr[li + 16 * k]; v[k] = vv; s1 += vv; s2 += vv * vv; }
#pragma unroll
        for (int o = 1; o < 16; o <<= 1) { s1 += __shfl_xor(s1, o); s2 += __shfl_xor(s2, o); }
        float mu = s1 * (1.f / 128.f);
        float rs = rsqrtf(s2 * (1.f / 128.f) - mu * mu + 1e-5f);
#pragma unroll
        for (int k = 0; k < 8; ++k) {
            int c = li + 16 * k;
            nrm[r][c]  = (v[k] - mu) * rs * g[c] + bb[c];
            ybuf[r][c] = v[k];
        }
    }
    __syncthreads();
    // f1 + gelu: thread -> cols c0..c0+3 (c0 = (t&127)*4), rows rg*8..+7
    {
        const int cg = t & 127, rg1 = t >> 7;
        const int c0 = cg * 4, rb0 = rg1 * 8;
        float4 bv = *(const float4*)&b1[c0];
        v2f accL[8], accH[8];
#pragma unroll
        for (int jr = 0; jr < 8; ++jr) { accL[jr] = (v2f){bv.x, bv.y}; accH[jr] = (v2f){bv.z, bv.w}; }
        for (int e = 0; e < 128; e += 4) {
            float4 nv[8];
#pragma unroll
            for (int jr = 0; jr < 8; ++jr) nv[jr] = *(const float4*)&nrm[rb0 + jr][e];
#pragma unroll
            for (int ei = 0; ei < 4; ++ei) {
                float4 w = *(const float4*)&w1[(e + ei) * 512 + c0];
                v2f wlo = {w.x, w.y}, whi = {w.z, w.w};
#pragma unroll
                for (int jr = 0; jr < 8; ++jr) {
                    float s = (ei == 0) ? nv[jr].x : (ei == 1) ? nv[jr].y : (ei == 2) ? nv[jr].z : nv[jr].w;
                    accL[jr] += wlo * s;
                    accH[jr] += whi * s;
                }
            }
        }
#pragma unroll
        for (int jr = 0; jr < 8; ++jr) {
            float4 hv = {gelu_exact(accL[jr].x), gelu_exact(accL[jr].y),
                         gelu_exact(accH[jr].x), gelu_exact(accH[jr].y)};
            *(float4*)&hb[rb0 + jr][c0] = hv;
        }
    }
    __syncthreads();
    // f2: thread -> cols c0..c0+3 (c0=(t&31)*4), rows (t>>5)*2..+1
    {
        const int cg = t & 31, rg2 = t >> 5;
        const int c0 = cg * 4, r0 = rg2 * 2;
        v2f a00 = {0.f, 0.f}, a01 = {0.f, 0.f}, a10 = {0.f, 0.f}, a11 = {0.f, 0.f};
        for (int f = 0; f < 512; f += 4) {
            float4 h0 = *(const float4*)&hb[r0][f];
            float4 h1 = *(const float4*)&hb[r0 + 1][f];
            float ha0[4] = {h0.x, h0.y, h0.z, h0.w};
            float ha1[4] = {h1.x, h1.y, h1.z, h1.w};
#pragma unroll
            for (int fi = 0; fi < 4; ++fi) {
                float4 w = *(const float4*)&w2[(f + fi) * 128 + c0];
                v2f wlo = {w.x, w.y}, whi = {w.z, w.w};
                a00 += wlo * ha0[fi]; a01 += whi * ha0[fi];
                a10 += wlo * ha1[fi]; a11 += whi * ha1[fi];
            }
        }
        float4 bv = *(const float4*)&b2[c0];
        float4 y0 = *(const float4*)&ybuf[r0][c0];
        float4 y1 = *(const float4*)&ybuf[r0 + 1][c0];
        float4 o0 = {y0.x + bv.x + a00.x, y0.y + bv.y + a00.y, y0.z + bv.z + a01.x, y0.w + bv.w + a01.y};
        float4 o1 = {y1.x + bv.x + a10.x, y1.y + bv.y + a10.y, y1.z + bv.z + a11.x, y1.w + bv.w + a11.y};
        *(float4*)&outp[(row0 + r0) * 128 + c0]     = o0;
        *(float4*)&outp[(row0 + r0 + 1) * 128 + c0] = o1;
    }
}

extern "C" void kernel_launch(void* const* d_in, const int* in_sizes, int n_in,
                              void* d_out, int out_size, void* d_ws, size_t ws_size,
                              hipStream_t stream) {
    const float* x      = (const float*)d_in[0];
    const float* ctx    = (const float*)d_in[1];
    const float* ctxn_g = (const float*)d_in[2];
    const float* ctxn_b = (const float*)d_in[3];
    const float* ctxp_w = (const float*)d_in[4];
    const float* ctxp_b = (const float*)d_in[5];
    const float* n1_g   = (const float*)d_in[6];
    const float* n1_b   = (const float*)d_in[7];
    const float* n1v_g  = (const float*)d_in[8];
    const float* n1v_b  = (const float*)d_in[9];
    const float* q_w    = (const float*)d_in[10];
    const float* q_b    = (const float*)d_in[11];
    const float* k_w    = (const float*)d_in[12];
    const float* k_b    = (const float*)d_in[13];
    const float* v_w    = (const float*)d_in[14];
    const float* v_b    = (const float*)d_in[15];
    const float* rpb    = (const float*)d_in[16];
    const float* proj_w = (const float*)d_in[17];
    const float* proj_b = (const float*)d_in[18];
    const float* n2_g   = (const float*)d_in[19];
    const float* n2_b   = (const float*)d_in[20];
    const float* f1_w   = (const float*)d_in[21];
    const float* f1_b   = (const float*)d_in[22];
    const float* f2_w   = (const float*)d_in[23];
    const float* f2_b   = (const float*)d_in[24];
    float* out = (float*)d_out;

    char* ws = (char*)d_ws;
    bf16*  ctxp = (bf16*)(ws);                    //  8,388,608 B  (B,HW,64)  bf16
    bf16*  qws  = (bf16*)(ws + 8388608);          // 16,777,216 B  (B,8,HW,16) bf16
    bf16*  kws  = (bf16*)(ws + 25165824);         // 16,777,216 B
    bf16*  vws  = (bf16*)(ws + 41943040);         // 16,777,216 B
    bf16*  ows  = (bf16*)(ws + 58720256);         // 16,777,216 B  (B,HW,128) bf16
    float* yws  = (float*)(ws + 75497472);        // 33,554,432 B  (B,HW,128) fp32

    k_ctx<<<1024, 256, 0, stream>>>(ctx, ctxn_g, ctxn_b, ctxp_w, ctxp_b, ctxp);
    k_qkv<<<4096, 256, 0, stream>>>(x, ctxp, n1_g, n1_b, n1v_g, n1v_b,
                                    q_w, q_b, k_w, k_b, v_w, v_b, qws, kws, vws);
    k_attn<<<2048, 256, 0, stream>>>(qws, kws, vws, rpb, ows);
    k_proj<<<4096, 256, 0, stream>>>(x, ows, proj_w, proj_b, yws);
    k_ffn<<<4096, 256, 0, stream>>>(yws, n2_g, n2_b, f1_w, f1_b, f2_w, f2_b, out);
}

// Round 4
// 891.451 us; speedup vs baseline: 10.7961x; 10.7961x over previous
//
#include <hip/hip_runtime.h>
#include <hip/hip_bf16.h>
#include <math.h>

typedef __hip_bfloat16 bf16;
typedef float v2f __attribute__((ext_vector_type(2)));
typedef float v4f __attribute__((ext_vector_type(4)));
typedef short v8s __attribute__((ext_vector_type(8)));

__device__ __forceinline__ float b2f(bf16 v) { return __bfloat162float(v); }
__device__ __forceinline__ float unpk_lo(unsigned u) { return __uint_as_float(u << 16); }
__device__ __forceinline__ float unpk_hi(unsigned u) { return __uint_as_float(u & 0xffff0000u); }
__device__ __forceinline__ v2f unpk2(unsigned u) {
    v2f r; r.x = __uint_as_float(u << 16); r.y = __uint_as_float(u & 0xffff0000u); return r;
}
__device__ __forceinline__ unsigned pk2(float a, float b) {
    unsigned ua = __float_as_uint(a);
    unsigned ub = __float_as_uint(b);
    ua = (ua + 0x7fffu + ((ua >> 16) & 1u)) >> 16;   // RNE to bf16
    ub = (ub + 0x7fffu + ((ub >> 16) & 1u)) >> 16;
    return ua | (ub << 16);
}
__device__ __forceinline__ short f2bs(float f) {
    unsigned u = __float_as_uint(f);
    u = (u + 0x7fffu + ((u >> 16) & 1u)) >> 16;
    return (short)u;
}
__device__ __forceinline__ float gelu_exact(float x) {
    return 0.5f * x * (1.f + erff(x * 0.70710678118654752440f));
}

// ---------------------------------------------------------------------------
// Repack a KxN fp32 weight into bf16 MFMA B-fragments for 16x16x32:
// element (k,n) -> dst[((kstep*(N/16) + n/16)*64 + (n&15) + 16*((k&31)>>3))*8 + (k&7)]
// ---------------------------------------------------------------------------
__global__ __launch_bounds__(256) void k_repack(const float* __restrict__ src,
                                                bf16* __restrict__ dst, int K, int N) {
    int idx = blockIdx.x * 256 + threadIdx.x;
    if (idx >= K * N) return;
    int k = idx / N, n = idx % N;
    int kstep = k >> 5, quad = (k & 31) >> 3, j = k & 7;
    int ntile = n >> 4, nn = n & 15;
    size_t di = ((((size_t)kstep * (N >> 4)) + ntile) * 64 + nn + (quad << 4)) * 8 + j;
    dst[di] = __float2bfloat16(src[idx]);
}

// ---------------------------------------------------------------------------
// Kernel 1: ctx = LN(context^T over EC=256) @ ctxp_w + ctxp_b -> (B,HW,64) bf16
// ---------------------------------------------------------------------------
__global__ __launch_bounds__(256) void k_ctx(const float* __restrict__ ctx,
                                             const float* __restrict__ g,
                                             const float* __restrict__ bb,
                                             const float* __restrict__ w,
                                             const float* __restrict__ pb,
                                             bf16* __restrict__ outp) {
    __shared__ unsigned tile[256][32];
    __shared__ float redS[8][64];
    __shared__ float redQ[8][64];
    __shared__ float s_mu[64], s_rs[64];
    const int t  = threadIdx.x;
    const int tx = t & 31;
    const int ty = t >> 5;
    const int b   = blockIdx.x >> 6;
    const int hw0 = (blockIdx.x & 63) << 6;
    const float* cbase = ctx + ((size_t)b * 256) * 4096 + hw0 + 2 * tx;
    float sa = 0.f, qa = 0.f, sb = 0.f, qb2 = 0.f;
    for (int e = ty; e < 256; e += 8) {
        float2 v = *(const float2*)(cbase + (size_t)e * 4096);
        tile[e][tx] = pk2(v.x, v.y);
        sa += v.x; qa += v.x * v.x;
        sb += v.y; qb2 += v.y * v.y;
    }
    redS[ty][2 * tx] = sa;  redS[ty][2 * tx + 1] = sb;
    redQ[ty][2 * tx] = qa;  redQ[ty][2 * tx + 1] = qb2;
    __syncthreads();
    if (t < 64) {
        float st = 0.f, qt = 0.f;
#pragma unroll
        for (int k = 0; k < 8; ++k) { st += redS[k][t]; qt += redQ[k][t]; }
        float mu = st * (1.f / 256.f);
        float var = qt * (1.f / 256.f) - mu * mu;
        s_mu[t] = mu;
        s_rs[t] = rsqrtf(var + 1e-5f);
    }
    __syncthreads();
    {
        float mu0 = s_mu[2 * tx], mu1 = s_mu[2 * tx + 1];
        float rs0 = s_rs[2 * tx], rs1 = s_rs[2 * tx + 1];
        for (int e = ty; e < 256; e += 8) {
            unsigned u = tile[e][tx];
            float ge = g[e], be = bb[e];
            float a0 = (unpk_lo(u) - mu0) * rs0 * ge + be;
            float a1 = (unpk_hi(u) - mu1) * rs1 * ge + be;
            tile[e][tx] = pk2(a0, a1);
        }
    }
    __syncthreads();
    const int tx2 = t & 63;
    const int ty2 = t >> 6;
    v2f acc[8];
#pragma unroll
    for (int q = 0; q < 8; ++q) { acc[q].x = pb[ty2 * 16 + 2 * q]; acc[q].y = pb[ty2 * 16 + 2 * q + 1]; }
    for (int e = 0; e < 256; ++e) {
        unsigned u = tile[e][tx2 >> 1];
        float a = (tx2 & 1) ? unpk_hi(u) : unpk_lo(u);
        const float4* wv = (const float4*)(w + e * 64 + ty2 * 16);
        float4 w0 = wv[0], w1 = wv[1], w2v = wv[2], w3 = wv[3];
        acc[0] += (v2f){w0.x, w0.y} * a;   acc[1] += (v2f){w0.z, w0.w} * a;
        acc[2] += (v2f){w1.x, w1.y} * a;   acc[3] += (v2f){w1.z, w1.w} * a;
        acc[4] += (v2f){w2v.x, w2v.y} * a; acc[5] += (v2f){w2v.z, w2v.w} * a;
        acc[6] += (v2f){w3.x, w3.y} * a;   acc[7] += (v2f){w3.z, w3.w} * a;
    }
    unsigned* orow = (unsigned*)(outp + ((size_t)b * 4096 + hw0 + tx2) * 64 + ty2 * 16);
    uint4 o0, o1;
    o0.x = pk2(acc[0].x, acc[0].y); o0.y = pk2(acc[1].x, acc[1].y);
    o0.z = pk2(acc[2].x, acc[2].y); o0.w = pk2(acc[3].x, acc[3].y);
    o1.x = pk2(acc[4].x, acc[4].y); o1.y = pk2(acc[5].x, acc[5].y);
    o1.z = pk2(acc[6].x, acc[6].y); o1.w = pk2(acc[7].x, acc[7].y);
    ((uint4*)orow)[0] = o0;
    ((uint4*)orow)[1] = o1;
}

// ---------------------------------------------------------------------------
// Kernel 2: LN(concat(x,ctx),192) -> q,k ; LN(x,128) -> v. 16 rows/block.
// ---------------------------------------------------------------------------
__global__ __launch_bounds__(256) void k_qkv(const float* __restrict__ x,
                                             const bf16* __restrict__ ctxp,
                                             const float* __restrict__ n1g, const float* __restrict__ n1b,
                                             const float* __restrict__ nvg, const float* __restrict__ nvb,
                                             const float* __restrict__ qw, const float* __restrict__ qb,
                                             const float* __restrict__ kw, const float* __restrict__ kb,
                                             const float* __restrict__ vw, const float* __restrict__ vb,
                                             bf16* __restrict__ qo, bf16* __restrict__ ko,
                                             bf16* __restrict__ vo) {
    __shared__ float qkn[16][192];
    __shared__ float vvn[16][128];
    const int t  = threadIdx.x;
    const int r  = t >> 4;
    const int li = t & 15;
    const int row0 = blockIdx.x * 16;
    {
        const float* xr = x + (size_t)(row0 + r) * 128;
        const bf16*  cr = ctxp + (size_t)(row0 + r) * 64;
        float xv[8], cv[4];
        float s1 = 0.f, s2 = 0.f;
#pragma unroll
        for (int k = 0; k < 8; ++k) { float v = xr[li + 16 * k]; xv[k] = v; s1 += v; s2 += v * v; }
        float t1 = s1, t2 = s2;
#pragma unroll
        for (int k = 0; k < 4; ++k) { float v = b2f(cr[li + 16 * k]); cv[k] = v; s1 += v; s2 += v * v; }
#pragma unroll
        for (int o = 1; o < 16; o <<= 1) {
            s1 += __shfl_xor(s1, o); s2 += __shfl_xor(s2, o);
            t1 += __shfl_xor(t1, o); t2 += __shfl_xor(t2, o);
        }
        float mu  = s1 * (1.f / 192.f);
        float rs  = rsqrtf(s2 * (1.f / 192.f) - mu * mu + 1e-5f);
        float muv = t1 * (1.f / 128.f);
        float rsv = rsqrtf(t2 * (1.f / 128.f) - muv * muv + 1e-5f);
#pragma unroll
        for (int k = 0; k < 8; ++k) {
            int c = li + 16 * k;
            qkn[r][c] = (xv[k] - mu) * rs * n1g[c] + n1b[c];
            vvn[r][c] = (xv[k] - muv) * rsv * nvg[c] + nvb[c];
        }
#pragma unroll
        for (int k = 0; k < 4; ++k) {
            int c = 128 + li + 16 * k;
            qkn[r][c] = (cv[k] - mu) * rs * n1g[c] + n1b[c];
        }
    }
    __syncthreads();
    const int cg = t & 31;
    const int rg = t >> 5;
    const int c0 = cg * 4;
    const int r0 = rg * 2;
    const int head = c0 >> 4;
    const int d    = c0 & 15;
    const int rowA = row0 + r0, rowB = rowA + 1;
    const int bA = rowA >> 12, hwA = rowA & 4095;
    const int bB = rowB >> 12, hwB = rowB & 4095;
    const size_t oiA = (((size_t)bA * 8 + head) * 4096 + hwA) * 16 + d;
    const size_t oiB = (((size_t)bB * 8 + head) * 4096 + hwB) * 16 + d;
    // ---- q ----
    {
        float4 bv = *(const float4*)&qb[c0];
        v2f a00 = {bv.x, bv.y}, a01 = {bv.z, bv.w};
        v2f a10 = a00, a11 = a01;
        for (int e = 0; e < 192; e += 4) {
            float4 n0 = *(const float4*)&qkn[r0][e];
            float4 n1 = *(const float4*)&qkn[r0 + 1][e];
            float na0[4] = {n0.x, n0.y, n0.z, n0.w};
            float na1[4] = {n1.x, n1.y, n1.z, n1.w};
#pragma unroll
            for (int ei = 0; ei < 4; ++ei) {
                float4 w = *(const float4*)&qw[(e + ei) * 128 + c0];
                v2f wlo = {w.x, w.y}, whi = {w.z, w.w};
                a00 += wlo * na0[ei]; a01 += whi * na0[ei];
                a10 += wlo * na1[ei]; a11 += whi * na1[ei];
            }
        }
        *(uint2*)(qo + oiA) = (uint2){pk2(a00.x * 0.25f, a00.y * 0.25f), pk2(a01.x * 0.25f, a01.y * 0.25f)};
        *(uint2*)(qo + oiB) = (uint2){pk2(a10.x * 0.25f, a10.y * 0.25f), pk2(a11.x * 0.25f, a11.y * 0.25f)};
    }
    // ---- k ----
    {
        float4 bv = *(const float4*)&kb[c0];
        v2f a00 = {bv.x, bv.y}, a01 = {bv.z, bv.w};
        v2f a10 = a00, a11 = a01;
        for (int e = 0; e < 192; e += 4) {
            float4 n0 = *(const float4*)&qkn[r0][e];
            float4 n1 = *(const float4*)&qkn[r0 + 1][e];
            float na0[4] = {n0.x, n0.y, n0.z, n0.w};
            float na1[4] = {n1.x, n1.y, n1.z, n1.w};
#pragma unroll
            for (int ei = 0; ei < 4; ++ei) {
                float4 w = *(const float4*)&kw[(e + ei) * 128 + c0];
                v2f wlo = {w.x, w.y}, whi = {w.z, w.w};
                a00 += wlo * na0[ei]; a01 += whi * na0[ei];
                a10 += wlo * na1[ei]; a11 += whi * na1[ei];
            }
        }
        *(uint2*)(ko + oiA) = (uint2){pk2(a00.x, a00.y), pk2(a01.x, a01.y)};
        *(uint2*)(ko + oiB) = (uint2){pk2(a10.x, a10.y), pk2(a11.x, a11.y)};
    }
    // ---- v ----
    {
        float4 bv = *(const float4*)&vb[c0];
        v2f a00 = {bv.x, bv.y}, a01 = {bv.z, bv.w};
        v2f a10 = a00, a11 = a01;
        for (int e = 0; e < 128; e += 4) {
            float4 n0 = *(const float4*)&vvn[r0][e];
            float4 n1 = *(const float4*)&vvn[r0 + 1][e];
            float na0[4] = {n0.x, n0.y, n0.z, n0.w};
            float na1[4] = {n1.x, n1.y, n1.z, n1.w};
#pragma unroll
            for (int ei = 0; ei < 4; ++ei) {
                float4 w = *(const float4*)&vw[(e + ei) * 128 + c0];
                v2f wlo = {w.x, w.y}, whi = {w.z, w.w};
                a00 += wlo * na0[ei]; a01 += whi * na0[ei];
                a10 += wlo * na1[ei]; a11 += whi * na1[ei];
            }
        }
        *(uint2*)(vo + oiA) = (uint2){pk2(a00.x, a00.y), pk2(a01.x, a01.y)};
        *(uint2*)(vo + oiB) = (uint2){pk2(a10.x, a10.y), pk2(a11.x, a11.y)};
    }
}

// ---------------------------------------------------------------------------
// Kernel 3: neighborhood attention (unchanged from round 3).
// ---------------------------------------------------------------------------
__global__ __launch_bounds__(256) void k_attn(const bf16* __restrict__ qws,
                                              const bf16* __restrict__ kws,
                                              const bf16* __restrict__ vws,
                                              const float* __restrict__ rpb,
                                              bf16* __restrict__ ows) {
    __shared__ unsigned kt[14][64][10];
    __shared__ unsigned vt[14][64][10];
    const int tid  = threadIdx.x;
    const int bh   = blockIdx.x >> 4;
    const int i0   = (blockIdx.x & 15) << 2;
    const int head = bh & 7;
    int start_min = i0 - 5; if (start_min < 0) start_min = 0; if (start_min > 53) start_min = 53;
    const unsigned* ku = (const unsigned*)kws;
    const unsigned* vu = (const unsigned*)vws;
    const size_t gbase = ((size_t)bh * 4096 + (size_t)start_min * 64) * 8;
    for (int idx = tid; idx < 7168; idx += 256) {
        int a = idx >> 9; int rem = idx & 511;
        int col = rem >> 3; int d2 = rem & 7;
        if (start_min + a < 64) {
            kt[a][col][d2] = ku[gbase + (size_t)a * 512 + rem];
            vt[a][col][d2] = vu[gbase + (size_t)a * 512 + rem];
        }
    }
    __syncthreads();
    const int wv = tid >> 6;
    const int j  = tid & 63;
    const int i  = i0 + wv;
    int start_i = i - 5; if (start_i < 0) start_i = 0; if (start_i > 53) start_i = 53;
    const int off = start_i - start_min;
    v2f qv[8];
    {
        const uint4* qp = (const uint4*)(qws + ((size_t)bh * 4096 + i * 64 + j) * 16);
        uint4 q0 = qp[0], q1 = qp[1];
        qv[0] = unpk2(q0.x); qv[1] = unpk2(q0.y); qv[2] = unpk2(q0.z); qv[3] = unpk2(q0.w);
        qv[4] = unpk2(q1.x); qv[5] = unpk2(q1.y); qv[6] = unpk2(q1.z); qv[7] = unpk2(q1.w);
    }
    int start_j = j - 5; if (start_j < 0) start_j = 0; if (start_j > 53) start_j = 53;
    float l = 0.f;
    v2f acc[8];
#pragma unroll
    for (int d = 0; d < 8; ++d) acc[d] = (v2f){0.f, 0.f};
    const float* rpb_h = rpb + head * 441 + (start_j - j + 10);
    for (int a = 0; a < 11; ++a) {
        const int r = off + a;
        const float* rb = rpb_h + (start_i + a - i + 10) * 21;
#pragma unroll
        for (int c = 0; c < 11; ++c) {
            const int jj = start_j + c;
            const unsigned* kp = kt[r][jj];
            v2f dv = qv[0] * unpk2(kp[0]);
            dv += qv[1] * unpk2(kp[1]);
            dv += qv[2] * unpk2(kp[2]);
            dv += qv[3] * unpk2(kp[3]);
            dv += qv[4] * unpk2(kp[4]);
            dv += qv[5] * unpk2(kp[5]);
            dv += qv[6] * unpk2(kp[6]);
            dv += qv[7] * unpk2(kp[7]);
            float s = rb[c] + dv.x + dv.y;
            float p = __expf(s);
            l += p;
            const unsigned* vp = vt[r][jj];
#pragma unroll
            for (int d2 = 0; d2 < 8; ++d2)
                acc[d2] += unpk2(vp[d2]) * p;
        }
    }
    float inv = 1.f / l;
    int b = bh >> 3;
    unsigned* op = (unsigned*)ows + ((size_t)b * 4096 + i * 64 + j) * 64 + head * 8;
#pragma unroll
    for (int d2 = 0; d2 < 8; ++d2)
        op[d2] = pk2(acc[d2].x * inv, acc[d2].y * inv);
}

// ---------------------------------------------------------------------------
// Kernel 4: y = x + concat(o, x) @ proj_w + proj_b -> fp32 ws (unchanged).
// ---------------------------------------------------------------------------
__global__ __launch_bounds__(256) void k_proj(const float* __restrict__ x,
                                              const bf16* __restrict__ ows,
                                              const float* __restrict__ pw,
                                              const float* __restrict__ pb,
                                              float* __restrict__ yws) {
    __shared__ float inb[16][256];
    const int t = threadIdx.x;
    const size_t row0 = (size_t)blockIdx.x * 16;
    for (int idx = t; idx < 2048; idx += 256) {
        int r = idx >> 7, c2 = idx & 127;
        inb[r][c2] = b2f(ows[(row0 + r) * 128 + c2]);
    }
    for (int idx = t; idx < 2048; idx += 256) {
        int r = idx >> 7, c2 = idx & 127;
        inb[r][128 + c2] = x[(row0 + r) * 128 + c2];
    }
    __syncthreads();
    const int cg = t & 31, rg = t >> 5;
    const int c0 = cg * 4, r0 = rg * 2;
    float4 bv = *(const float4*)&pb[c0];
    v2f a00 = {bv.x, bv.y}, a01 = {bv.z, bv.w};
    v2f a10 = a00, a11 = a01;
    for (int e = 0; e < 256; e += 4) {
        float4 n0 = *(const float4*)&inb[r0][e];
        float4 n1 = *(const float4*)&inb[r0 + 1][e];
        float na0[4] = {n0.x, n0.y, n0.z, n0.w};
        float na1[4] = {n1.x, n1.y, n1.z, n1.w};
#pragma unroll
        for (int ei = 0; ei < 4; ++ei) {
            float4 w = *(const float4*)&pw[(e + ei) * 128 + c0];
            v2f wlo = {w.x, w.y}, whi = {w.z, w.w};
            a00 += wlo * na0[ei]; a01 += whi * na0[ei];
            a10 += wlo * na1[ei]; a11 += whi * na1[ei];
        }
    }
    float4 x0 = *(const float4*)&inb[r0][128 + c0];
    float4 x1 = *(const float4*)&inb[r0 + 1][128 + c0];
    float4 o0 = {x0.x + a00.x, x0.y + a00.y, x0.z + a01.x, x0.w + a01.y};
    float4 o1 = {x1.x + a10.x, x1.y + a10.y, x1.z + a11.x, x1.w + a11.y};
    *(float4*)&yws[(row0 + r0) * 128 + c0]     = o0;
    *(float4*)&yws[(row0 + r0 + 1) * 128 + c0] = o1;
}

// ---------------------------------------------------------------------------
// Kernel 5 (MFMA): ffn = gelu(LN(y)@f1+b1)@f2+b2; out = y + ffn.
// 32 rows/block, 4 waves. f1: wave owns 128 N-cols (2 m-tiles x 8 n-tiles).
// f2: wave owns 2 n-tiles x 2 m-tiles, K=512. A-frags via padded LDS
// (row+8 bf16 -> 16B aligned ds_read_b128, 2-way bank alias = free).
// B-frags from pre-repacked bf16 fragment buffers (one 16B load each).
// ---------------------------------------------------------------------------
__global__ __launch_bounds__(256) void k_ffn(const float* __restrict__ yws,
                                             const float* __restrict__ g, const float* __restrict__ bb,
                                             const bf16* __restrict__ w1f, const float* __restrict__ b1,
                                             const bf16* __restrict__ w2f, const float* __restrict__ b2,
                                             float* __restrict__ outp) {
    __shared__ short An[32][136];
    __shared__ short Hs[32][520];
    const int t = threadIdx.x;
    const size_t row0 = (size_t)blockIdx.x * 32;
    // ---- LN: 8 threads/row, each handles 16 contiguous cols ----
    {
        const int r = t >> 3, li = t & 7;
        const float* yr = yws + (row0 + r) * 128 + li * 16;
        float v[16];
        float s1 = 0.f, s2 = 0.f;
#pragma unroll
        for (int k4 = 0; k4 < 4; ++k4) {
            float4 vv = *(const float4*)(yr + 4 * k4);
            v[4 * k4 + 0] = vv.x; v[4 * k4 + 1] = vv.y; v[4 * k4 + 2] = vv.z; v[4 * k4 + 3] = vv.w;
            s1 += vv.x + vv.y + vv.z + vv.w;
            s2 += vv.x * vv.x + vv.y * vv.y + vv.z * vv.z + vv.w * vv.w;
        }
#pragma unroll
        for (int o = 1; o < 8; o <<= 1) { s1 += __shfl_xor(s1, o); s2 += __shfl_xor(s2, o); }
        float mu = s1 * (1.f / 128.f);
        float rs = rsqrtf(s2 * (1.f / 128.f) - mu * mu + 1e-5f);
        v8s lo, hi;
#pragma unroll
        for (int k = 0; k < 8; ++k) {
            int c = li * 16 + k;
            lo[k] = f2bs((v[k] - mu) * rs * g[c] + bb[c]);
        }
#pragma unroll
        for (int k = 0; k < 8; ++k) {
            int c = li * 16 + 8 + k;
            hi[k] = f2bs((v[8 + k] - mu) * rs * g[c] + bb[c]);
        }
        *(v8s*)&An[r][li * 16]     = lo;
        *(v8s*)&An[r][li * 16 + 8] = hi;
    }
    __syncthreads();
    const int lane = t & 63, wv = t >> 6;
    const int m = lane & 15, quad = lane >> 4;
    // ---- f1: C1[32][512], wave wv owns cols wv*128..+127 ----
    v4f acc1[2][8];
#pragma unroll
    for (int a = 0; a < 2; ++a)
#pragma unroll
        for (int b = 0; b < 8; ++b) acc1[a][b] = (v4f){0.f, 0.f, 0.f, 0.f};
    const int n0w = wv * 128;
#pragma unroll
    for (int ks = 0; ks < 4; ++ks) {
        v8s a0 = *(const v8s*)&An[m][ks * 32 + quad * 8];
        v8s a1 = *(const v8s*)&An[m + 16][ks * 32 + quad * 8];
        const v8s* bp = (const v8s*)w1f + ((size_t)ks * 32 + (n0w >> 4)) * 64 + lane;
#pragma unroll
        for (int nt = 0; nt < 8; ++nt) {
            v8s b = bp[nt * 64];
            acc1[0][nt] = __builtin_amdgcn_mfma_f32_16x16x32_bf16(a0, b, acc1[0][nt], 0, 0, 0);
            acc1[1][nt] = __builtin_amdgcn_mfma_f32_16x16x32_bf16(a1, b, acc1[1][nt], 0, 0, 0);
        }
    }
    // ---- bias + gelu -> Hs (D layout: col=lane&15, row=quad*4+reg) ----
#pragma unroll
    for (int nt = 0; nt < 8; ++nt) {
        int n = n0w + nt * 16 + m;
        float b1v = b1[n];
#pragma unroll
        for (int mt = 0; mt < 2; ++mt)
#pragma unroll
            for (int rg = 0; rg < 4; ++rg)
                Hs[mt * 16 + quad * 4 + rg][n] = f2bs(gelu_exact(acc1[mt][nt][rg] + b1v));
    }
    __syncthreads();
    // ---- f2: C2[32][128], wave wv owns n-tiles {2wv, 2wv+1} ----
    v4f acc2[2][2];
#pragma unroll
    for (int a = 0; a < 2; ++a)
#pragma unroll
        for (int b = 0; b < 2; ++b) acc2[a][b] = (v4f){0.f, 0.f, 0.f, 0.f};
    const int ntb = wv * 2;
#pragma unroll
    for (int ks = 0; ks < 16; ++ks) {
        v8s a0 = *(const v8s*)&Hs[m][ks * 32 + quad * 8];
        v8s a1 = *(const v8s*)&Hs[m + 16][ks * 32 + quad * 8];
        const v8s* bp = (const v8s*)w2f + ((size_t)ks * 8 + ntb) * 64 + lane;
#pragma unroll
        for (int nt = 0; nt < 2; ++nt) {
            v8s b = bp[nt * 64];
            acc2[0][nt] = __builtin_amdgcn_mfma_f32_16x16x32_bf16(a0, b, acc2[0][nt], 0, 0, 0);
            acc2[1][nt] = __builtin_amdgcn_mfma_f32_16x16x32_bf16(a1, b, acc2[1][nt], 0, 0, 0);
        }
    }
    // ---- epilogue: out = y + b2 + ffn ----
#pragma unroll
    for (int nt = 0; nt < 2; ++nt) {
        int n = (ntb + nt) * 16 + m;
        float b2v = b2[n];
#pragma unroll
        for (int mt = 0; mt < 2; ++mt)
#pragma unroll
            for (int rg = 0; rg < 4; ++rg) {
                int row = mt * 16 + quad * 4 + rg;
                size_t gi = (row0 + row) * 128 + n;
                outp[gi] = yws[gi] + b2v + acc2[mt][nt][rg];
            }
    }
}

extern "C" void kernel_launch(void* const* d_in, const int* in_sizes, int n_in,
                              void* d_out, int out_size, void* d_ws, size_t ws_size,
                              hipStream_t stream) {
    const float* x      = (const float*)d_in[0];
    const float* ctx    = (const float*)d_in[1];
    const float* ctxn_g = (const float*)d_in[2];
    const float* ctxn_b = (const float*)d_in[3];
    const float* ctxp_w = (const float*)d_in[4];
    const float* ctxp_b = (const float*)d_in[5];
    const float* n1_g   = (const float*)d_in[6];
    const float* n1_b   = (const float*)d_in[7];
    const float* n1v_g  = (const float*)d_in[8];
    const float* n1v_b  = (const float*)d_in[9];
    const float* q_w    = (const float*)d_in[10];
    const float* q_b    = (const float*)d_in[11];
    const float* k_w    = (const float*)d_in[12];
    const float* k_b    = (const float*)d_in[13];
    const float* v_w    = (const float*)d_in[14];
    const float* v_b    = (const float*)d_in[15];
    const float* rpb    = (const float*)d_in[16];
    const float* proj_w = (const float*)d_in[17];
    const float* proj_b = (const float*)d_in[18];
    const float* n2_g   = (const float*)d_in[19];
    const float* n2_b   = (const float*)d_in[20];
    const float* f1_w   = (const float*)d_in[21];
    const float* f1_b   = (const float*)d_in[22];
    const float* f2_w   = (const float*)d_in[23];
    const float* f2_b   = (const float*)d_in[24];
    float* out = (float*)d_out;

    char* ws = (char*)d_ws;
    bf16*  ctxp = (bf16*)(ws);                    //  8,388,608 B  (B,HW,64)  bf16
    bf16*  qws  = (bf16*)(ws + 8388608);          // 16,777,216 B  (B,8,HW,16) bf16
    bf16*  kws  = (bf16*)(ws + 25165824);         // 16,777,216 B
    bf16*  vws  = (bf16*)(ws + 41943040);         // 16,777,216 B
    bf16*  ows  = (bf16*)(ws + 58720256);         // 16,777,216 B  (B,HW,128) bf16
    float* yws  = (float*)(ws + 75497472);        // 33,554,432 B  (B,HW,128) fp32
    bf16*  w1f  = (bf16*)(ws + 109051904);        //    131,072 B  f1_w frags
    bf16*  w2f  = (bf16*)(ws + 109182976);        //    131,072 B  f2_w frags
    // total 109,314,048 B

    k_repack<<<256, 256, 0, stream>>>(f1_w, w1f, 128, 512);
    k_repack<<<256, 256, 0, stream>>>(f2_w, w2f, 512, 128);
    k_ctx<<<1024, 256, 0, stream>>>(ctx, ctxn_g, ctxn_b, ctxp_w, ctxp_b, ctxp);
    k_qkv<<<4096, 256, 0, stream>>>(x, ctxp, n1_g, n1_b, n1v_g, n1v_b,
                                    q_w, q_b, k_w, k_b, v_w, v_b, qws, kws, vws);
    k_attn<<<2048, 256, 0, stream>>>(qws, kws, vws, rpb, ows);
    k_proj<<<4096, 256, 0, stream>>>(x, ows, proj_w, proj_b, yws);
    k_ffn<<<2048, 256, 0, stream>>>(yws, n2_g, n2_b, w1f, f1_b, w2f, f2_b, out);
}

// Round 5
// 580.181 us; speedup vs baseline: 16.5882x; 1.5365x over previous
//
#include <hip/hip_runtime.h>
#include <hip/hip_bf16.h>
#include <math.h>

typedef __hip_bfloat16 bf16;
typedef float v2f __attribute__((ext_vector_type(2)));
typedef float v4f __attribute__((ext_vector_type(4)));
typedef short v8s __attribute__((ext_vector_type(8)));

__device__ __forceinline__ float b2f(bf16 v) { return __bfloat162float(v); }
__device__ __forceinline__ float unpk_lo(unsigned u) { return __uint_as_float(u << 16); }
__device__ __forceinline__ float unpk_hi(unsigned u) { return __uint_as_float(u & 0xffff0000u); }
__device__ __forceinline__ v2f unpk2(unsigned u) {
    v2f r; r.x = __uint_as_float(u << 16); r.y = __uint_as_float(u & 0xffff0000u); return r;
}
__device__ __forceinline__ unsigned pk2(float a, float b) {
    unsigned ua = __float_as_uint(a);
    unsigned ub = __float_as_uint(b);
    ua = (ua + 0x7fffu + ((ua >> 16) & 1u)) >> 16;   // RNE to bf16
    ub = (ub + 0x7fffu + ((ub >> 16) & 1u)) >> 16;
    return ua | (ub << 16);
}
__device__ __forceinline__ short f2bs(float f) {
    unsigned u = __float_as_uint(f);
    u = (u + 0x7fffu + ((u >> 16) & 1u)) >> 16;
    return (short)u;
}
__device__ __forceinline__ float gelu_exact(float x) {
    return 0.5f * x * (1.f + erff(x * 0.70710678118654752440f));
}

// ---------------------------------------------------------------------------
// Repack a KxN fp32 weight into bf16 MFMA B-fragments for 16x16x32:
// (k,n) -> dst[((kstep*(N/16) + n/16)*64 + (n&15) + 16*((k&31)>>3))*8 + (k&7)]
// ---------------------------------------------------------------------------
__global__ __launch_bounds__(256) void k_repack(const float* __restrict__ src,
                                                bf16* __restrict__ dst, int K, int N) {
    int idx = blockIdx.x * 256 + threadIdx.x;
    if (idx >= K * N) return;
    int k = idx / N, n = idx % N;
    int kstep = k >> 5, quad = (k & 31) >> 3, j = k & 7;
    int ntile = n >> 4, nn = n & 15;
    size_t di = ((((size_t)kstep * (N >> 4)) + ntile) * 64 + nn + (quad << 4)) * 8 + j;
    dst[di] = __float2bfloat16(src[idx]);
}

// ---------------------------------------------------------------------------
// Kernel 1: ctx = LN(context^T over EC=256) @ ctxp_w + ctxp_b -> (B,HW,64) bf16
// ---------------------------------------------------------------------------
__global__ __launch_bounds__(256) void k_ctx(const float* __restrict__ ctx,
                                             const float* __restrict__ g,
                                             const float* __restrict__ bb,
                                             const float* __restrict__ w,
                                             const float* __restrict__ pb,
                                             bf16* __restrict__ outp) {
    __shared__ unsigned tile[256][32];
    __shared__ float redS[8][64];
    __shared__ float redQ[8][64];
    __shared__ float s_mu[64], s_rs[64];
    const int t  = threadIdx.x;
    const int tx = t & 31;
    const int ty = t >> 5;
    const int b   = blockIdx.x >> 6;
    const int hw0 = (blockIdx.x & 63) << 6;
    const float* cbase = ctx + ((size_t)b * 256) * 4096 + hw0 + 2 * tx;
    float sa = 0.f, qa = 0.f, sb = 0.f, qb2 = 0.f;
    for (int e = ty; e < 256; e += 8) {
        float2 v = *(const float2*)(cbase + (size_t)e * 4096);
        tile[e][tx] = pk2(v.x, v.y);
        sa += v.x; qa += v.x * v.x;
        sb += v.y; qb2 += v.y * v.y;
    }
    redS[ty][2 * tx] = sa;  redS[ty][2 * tx + 1] = sb;
    redQ[ty][2 * tx] = qa;  redQ[ty][2 * tx + 1] = qb2;
    __syncthreads();
    if (t < 64) {
        float st = 0.f, qt = 0.f;
#pragma unroll
        for (int k = 0; k < 8; ++k) { st += redS[k][t]; qt += redQ[k][t]; }
        float mu = st * (1.f / 256.f);
        float var = qt * (1.f / 256.f) - mu * mu;
        s_mu[t] = mu;
        s_rs[t] = rsqrtf(var + 1e-5f);
    }
    __syncthreads();
    {
        float mu0 = s_mu[2 * tx], mu1 = s_mu[2 * tx + 1];
        float rs0 = s_rs[2 * tx], rs1 = s_rs[2 * tx + 1];
        for (int e = ty; e < 256; e += 8) {
            unsigned u = tile[e][tx];
            float ge = g[e], be = bb[e];
            float a0 = (unpk_lo(u) - mu0) * rs0 * ge + be;
            float a1 = (unpk_hi(u) - mu1) * rs1 * ge + be;
            tile[e][tx] = pk2(a0, a1);
        }
    }
    __syncthreads();
    const int tx2 = t & 63;
    const int ty2 = t >> 6;
    v2f acc[8];
#pragma unroll
    for (int q = 0; q < 8; ++q) { acc[q].x = pb[ty2 * 16 + 2 * q]; acc[q].y = pb[ty2 * 16 + 2 * q + 1]; }
    for (int e = 0; e < 256; ++e) {
        unsigned u = tile[e][tx2 >> 1];
        float a = (tx2 & 1) ? unpk_hi(u) : unpk_lo(u);
        const float4* wv = (const float4*)(w + e * 64 + ty2 * 16);
        float4 w0 = wv[0], w1 = wv[1], w2v = wv[2], w3 = wv[3];
        acc[0] += (v2f){w0.x, w0.y} * a;   acc[1] += (v2f){w0.z, w0.w} * a;
        acc[2] += (v2f){w1.x, w1.y} * a;   acc[3] += (v2f){w1.z, w1.w} * a;
        acc[4] += (v2f){w2v.x, w2v.y} * a; acc[5] += (v2f){w2v.z, w2v.w} * a;
        acc[6] += (v2f){w3.x, w3.y} * a;   acc[7] += (v2f){w3.z, w3.w} * a;
    }
    unsigned* orow = (unsigned*)(outp + ((size_t)b * 4096 + hw0 + tx2) * 64 + ty2 * 16);
    uint4 o0, o1;
    o0.x = pk2(acc[0].x, acc[0].y); o0.y = pk2(acc[1].x, acc[1].y);
    o0.z = pk2(acc[2].x, acc[2].y); o0.w = pk2(acc[3].x, acc[3].y);
    o1.x = pk2(acc[4].x, acc[4].y); o1.y = pk2(acc[5].x, acc[5].y);
    o1.z = pk2(acc[6].x, acc[6].y); o1.w = pk2(acc[7].x, acc[7].y);
    ((uint4*)orow)[0] = o0;
    ((uint4*)orow)[1] = o1;
}

// ---------------------------------------------------------------------------
// Kernel 2 (MFMA): LN(concat(x,ctx),192) -> q,k ; LN(x,128) -> v.
// 32 rows/block, 4 waves; wave owns 2 n-tiles (32 cols) for q,k,v.
// A-tiles in padded LDS; B-frags pre-repacked. grid 2048, blk 256.
// ---------------------------------------------------------------------------
__global__ __launch_bounds__(256) void k_qkv(const float* __restrict__ x,
                                             const bf16* __restrict__ ctxp,
                                             const float* __restrict__ n1g, const float* __restrict__ n1b,
                                             const float* __restrict__ nvg, const float* __restrict__ nvb,
                                             const bf16* __restrict__ qwf, const float* __restrict__ qb,
                                             const bf16* __restrict__ kwf, const float* __restrict__ kb,
                                             const bf16* __restrict__ vwf, const float* __restrict__ vb,
                                             bf16* __restrict__ qo, bf16* __restrict__ ko,
                                             bf16* __restrict__ vo) {
    __shared__ short Aqk[32][200];   // 192 + 8 pad (400 B row stride)
    __shared__ short Av[32][136];    // 128 + 8 pad (272 B row stride)
    const int t = threadIdx.x;
    const size_t row0 = (size_t)blockIdx.x * 32;
    // ---- LN stage: 8 threads/row; 16 x-cols + 8 ctx-cols per thread ----
    {
        const int r = t >> 3, li = t & 7;
        const float* xr = x + (row0 + r) * 128 + li * 16;
        float v[16];
        float sx1 = 0.f, sx2 = 0.f;
#pragma unroll
        for (int k4 = 0; k4 < 4; ++k4) {
            float4 vv = *(const float4*)(xr + 4 * k4);
            v[4 * k4 + 0] = vv.x; v[4 * k4 + 1] = vv.y; v[4 * k4 + 2] = vv.z; v[4 * k4 + 3] = vv.w;
            sx1 += vv.x + vv.y + vv.z + vv.w;
            sx2 += vv.x * vv.x + vv.y * vv.y + vv.z * vv.z + vv.w * vv.w;
        }
        float cv[8];
        float sc1 = 0.f, sc2 = 0.f;
        {
            uint4 cu = *(const uint4*)(ctxp + (row0 + r) * 64 + li * 8);
            v2f p0 = unpk2(cu.x), p1 = unpk2(cu.y), p2 = unpk2(cu.z), p3 = unpk2(cu.w);
            cv[0] = p0.x; cv[1] = p0.y; cv[2] = p1.x; cv[3] = p1.y;
            cv[4] = p2.x; cv[5] = p2.y; cv[6] = p3.x; cv[7] = p3.y;
#pragma unroll
            for (int k = 0; k < 8; ++k) { sc1 += cv[k]; sc2 += cv[k] * cv[k]; }
        }
#pragma unroll
        for (int o = 1; o < 8; o <<= 1) {
            sx1 += __shfl_xor(sx1, o); sx2 += __shfl_xor(sx2, o);
            sc1 += __shfl_xor(sc1, o); sc2 += __shfl_xor(sc2, o);
        }
        float mu  = (sx1 + sc1) * (1.f / 192.f);
        float rs  = rsqrtf((sx2 + sc2) * (1.f / 192.f) - mu * mu + 1e-5f);
        float muv = sx1 * (1.f / 128.f);
        float rsv = rsqrtf(sx2 * (1.f / 128.f) - muv * muv + 1e-5f);
        v8s q0, q1, vv0, vv1, cc;
#pragma unroll
        for (int k = 0; k < 8; ++k) {
            int c = li * 16 + k;
            q0[k]  = f2bs((v[k] - mu) * rs * n1g[c] + n1b[c]);
            vv0[k] = f2bs((v[k] - muv) * rsv * nvg[c] + nvb[c]);
        }
#pragma unroll
        for (int k = 0; k < 8; ++k) {
            int c = li * 16 + 8 + k;
            q1[k]  = f2bs((v[8 + k] - mu) * rs * n1g[c] + n1b[c]);
            vv1[k] = f2bs((v[8 + k] - muv) * rsv * nvg[c] + nvb[c]);
        }
#pragma unroll
        for (int k = 0; k < 8; ++k) {
            int c = 128 + li * 8 + k;
            cc[k] = f2bs((cv[k] - mu) * rs * n1g[c] + n1b[c]);
        }
        *(v8s*)&Aqk[r][li * 16]     = q0;
        *(v8s*)&Aqk[r][li * 16 + 8] = q1;
        *(v8s*)&Aqk[r][128 + li * 8] = cc;
        *(v8s*)&Av[r][li * 16]     = vv0;
        *(v8s*)&Av[r][li * 16 + 8] = vv1;
    }
    __syncthreads();
    const int lane = t & 63, wv = t >> 6;
    const int m = lane & 15, quad = lane >> 4;
    const int ntb = wv * 2;
    v4f aq[2][2], ak[2][2], av[2][2];
#pragma unroll
    for (int a = 0; a < 2; ++a)
#pragma unroll
        for (int b = 0; b < 2; ++b) {
            aq[a][b] = (v4f){0.f, 0.f, 0.f, 0.f};
            ak[a][b] = (v4f){0.f, 0.f, 0.f, 0.f};
            av[a][b] = (v4f){0.f, 0.f, 0.f, 0.f};
        }
#pragma unroll
    for (int ks = 0; ks < 6; ++ks) {
        v8s a0 = *(const v8s*)&Aqk[m][ks * 32 + quad * 8];
        v8s a1 = *(const v8s*)&Aqk[m + 16][ks * 32 + quad * 8];
        const v8s* bpq = (const v8s*)qwf + ((size_t)ks * 8 + ntb) * 64 + lane;
        const v8s* bpk = (const v8s*)kwf + ((size_t)ks * 8 + ntb) * 64 + lane;
#pragma unroll
        for (int nt = 0; nt < 2; ++nt) {
            v8s bq = bpq[nt * 64];
            v8s bk = bpk[nt * 64];
            aq[0][nt] = __builtin_amdgcn_mfma_f32_16x16x32_bf16(a0, bq, aq[0][nt], 0, 0, 0);
            aq[1][nt] = __builtin_amdgcn_mfma_f32_16x16x32_bf16(a1, bq, aq[1][nt], 0, 0, 0);
            ak[0][nt] = __builtin_amdgcn_mfma_f32_16x16x32_bf16(a0, bk, ak[0][nt], 0, 0, 0);
            ak[1][nt] = __builtin_amdgcn_mfma_f32_16x16x32_bf16(a1, bk, ak[1][nt], 0, 0, 0);
        }
    }
#pragma unroll
    for (int ks = 0; ks < 4; ++ks) {
        v8s a0 = *(const v8s*)&Av[m][ks * 32 + quad * 8];
        v8s a1 = *(const v8s*)&Av[m + 16][ks * 32 + quad * 8];
        const v8s* bpv = (const v8s*)vwf + ((size_t)ks * 8 + ntb) * 64 + lane;
#pragma unroll
        for (int nt = 0; nt < 2; ++nt) {
            v8s bv = bpv[nt * 64];
            av[0][nt] = __builtin_amdgcn_mfma_f32_16x16x32_bf16(a0, bv, av[0][nt], 0, 0, 0);
            av[1][nt] = __builtin_amdgcn_mfma_f32_16x16x32_bf16(a1, bv, av[1][nt], 0, 0, 0);
        }
    }
    // ---- epilogue: scatter bf16 into (B,8,HW,16) ----
#pragma unroll
    for (int nt = 0; nt < 2; ++nt) {
        int n = (ntb + nt) * 16 + m;
        int head = n >> 4, d = n & 15;
        float qbv = qb[n], kbv = kb[n], vbv = vb[n];
#pragma unroll
        for (int mt = 0; mt < 2; ++mt)
#pragma unroll
            for (int rg = 0; rg < 4; ++rg) {
                int rowg = (int)row0 + mt * 16 + quad * 4 + rg;
                int b = rowg >> 12, hw = rowg & 4095;
                size_t oi = (((size_t)b * 8 + head) * 4096 + hw) * 16 + d;
                qo[oi] = __float2bfloat16((aq[mt][nt][rg] + qbv) * 0.25f);
                ko[oi] = __float2bfloat16(ak[mt][nt][rg] + kbv);
                vo[oi] = __float2bfloat16(av[mt][nt][rg] + vbv);
            }
    }
}

// ---------------------------------------------------------------------------
// Kernel 3: neighborhood attention (unchanged).
// ---------------------------------------------------------------------------
__global__ __launch_bounds__(256) void k_attn(const bf16* __restrict__ qws,
                                              const bf16* __restrict__ kws,
                                              const bf16* __restrict__ vws,
                                              const float* __restrict__ rpb,
                                              bf16* __restrict__ ows) {
    __shared__ unsigned kt[14][64][10];
    __shared__ unsigned vt[14][64][10];
    const int tid  = threadIdx.x;
    const int bh   = blockIdx.x >> 4;
    const int i0   = (blockIdx.x & 15) << 2;
    const int head = bh & 7;
    int start_min = i0 - 5; if (start_min < 0) start_min = 0; if (start_min > 53) start_min = 53;
    const unsigned* ku = (const unsigned*)kws;
    const unsigned* vu = (const unsigned*)vws;
    const size_t gbase = ((size_t)bh * 4096 + (size_t)start_min * 64) * 8;
    for (int idx = tid; idx < 7168; idx += 256) {
        int a = idx >> 9; int rem = idx & 511;
        int col = rem >> 3; int d2 = rem & 7;
        if (start_min + a < 64) {
            kt[a][col][d2] = ku[gbase + (size_t)a * 512 + rem];
            vt[a][col][d2] = vu[gbase + (size_t)a * 512 + rem];
        }
    }
    __syncthreads();
    const int wv = tid >> 6;
    const int j  = tid & 63;
    const int i  = i0 + wv;
    int start_i = i - 5; if (start_i < 0) start_i = 0; if (start_i > 53) start_i = 53;
    const int off = start_i - start_min;
    v2f qv[8];
    {
        const uint4* qp = (const uint4*)(qws + ((size_t)bh * 4096 + i * 64 + j) * 16);
        uint4 q0 = qp[0], q1 = qp[1];
        qv[0] = unpk2(q0.x); qv[1] = unpk2(q0.y); qv[2] = unpk2(q0.z); qv[3] = unpk2(q0.w);
        qv[4] = unpk2(q1.x); qv[5] = unpk2(q1.y); qv[6] = unpk2(q1.z); qv[7] = unpk2(q1.w);
    }
    int start_j = j - 5; if (start_j < 0) start_j = 0; if (start_j > 53) start_j = 53;
    float l = 0.f;
    v2f acc[8];
#pragma unroll
    for (int d = 0; d < 8; ++d) acc[d] = (v2f){0.f, 0.f};
    const float* rpb_h = rpb + head * 441 + (start_j - j + 10);
    for (int a = 0; a < 11; ++a) {
        const int r = off + a;
        const float* rb = rpb_h + (start_i + a - i + 10) * 21;
#pragma unroll
        for (int c = 0; c < 11; ++c) {
            const int jj = start_j + c;
            const unsigned* kp = kt[r][jj];
            v2f dv = qv[0] * unpk2(kp[0]);
            dv += qv[1] * unpk2(kp[1]);
            dv += qv[2] * unpk2(kp[2]);
            dv += qv[3] * unpk2(kp[3]);
            dv += qv[4] * unpk2(kp[4]);
            dv += qv[5] * unpk2(kp[5]);
            dv += qv[6] * unpk2(kp[6]);
            dv += qv[7] * unpk2(kp[7]);
            float s = rb[c] + dv.x + dv.y;
            float p = __expf(s);
            l += p;
            const unsigned* vp = vt[r][jj];
#pragma unroll
            for (int d2 = 0; d2 < 8; ++d2)
                acc[d2] += unpk2(vp[d2]) * p;
        }
    }
    float inv = 1.f / l;
    int b = bh >> 3;
    unsigned* op = (unsigned*)ows + ((size_t)b * 4096 + i * 64 + j) * 64 + head * 8;
#pragma unroll
    for (int d2 = 0; d2 < 8; ++d2)
        op[d2] = pk2(acc[d2].x * inv, acc[d2].y * inv);
}

// ---------------------------------------------------------------------------
// Kernel 4 (MFMA): y = x + concat(o, x) @ proj_w + proj_b -> fp32 ws.
// 32 rows/block, K=256, wave owns 2 n-tiles. grid 2048, blk 256.
// ---------------------------------------------------------------------------
__global__ __launch_bounds__(256) void k_proj(const float* __restrict__ x,
                                              const bf16* __restrict__ ows,
                                              const bf16* __restrict__ pwf,
                                              const float* __restrict__ pb,
                                              float* __restrict__ yws) {
    __shared__ short An[32][264];   // 256 + 8 pad (528 B row stride)
    const int t = threadIdx.x;
    const size_t row0 = (size_t)blockIdx.x * 32;
    // stage: 8 threads/row: o cols li*16..+16 (bf16 raw), x cols li*16..+16 (cvt)
    {
        const int r = t >> 3, li = t & 7;
        // o part: already bf16 — copy 16 shorts
        const uint4* osrc = (const uint4*)(ows + (row0 + r) * 128 + li * 16);
        uint4 o0 = osrc[0], o1 = osrc[1];
        *(uint4*)&An[r][li * 16]     = o0;
        *(uint4*)&An[r][li * 16 + 8] = o1;
        const float* xr = x + (row0 + r) * 128 + li * 16;
        v8s xa, xb;
#pragma unroll
        for (int k4 = 0; k4 < 2; ++k4) {
            float4 vv = *(const float4*)(xr + 4 * k4);
            xa[4 * k4 + 0] = f2bs(vv.x); xa[4 * k4 + 1] = f2bs(vv.y);
            xa[4 * k4 + 2] = f2bs(vv.z); xa[4 * k4 + 3] = f2bs(vv.w);
        }
#pragma unroll
        for (int k4 = 0; k4 < 2; ++k4) {
            float4 vv = *(const float4*)(xr + 8 + 4 * k4);
            xb[4 * k4 + 0] = f2bs(vv.x); xb[4 * k4 + 1] = f2bs(vv.y);
            xb[4 * k4 + 2] = f2bs(vv.z); xb[4 * k4 + 3] = f2bs(vv.w);
        }
        *(v8s*)&An[r][128 + li * 16]     = xa;
        *(v8s*)&An[r][128 + li * 16 + 8] = xb;
    }
    __syncthreads();
    const int lane = t & 63, wv = t >> 6;
    const int m = lane & 15, quad = lane >> 4;
    const int ntb = wv * 2;
    v4f acc[2][2];
#pragma unroll
    for (int a = 0; a < 2; ++a)
#pragma unroll
        for (int b = 0; b < 2; ++b) acc[a][b] = (v4f){0.f, 0.f, 0.f, 0.f};
#pragma unroll
    for (int ks = 0; ks < 8; ++ks) {
        v8s a0 = *(const v8s*)&An[m][ks * 32 + quad * 8];
        v8s a1 = *(const v8s*)&An[m + 16][ks * 32 + quad * 8];
        const v8s* bp = (const v8s*)pwf + ((size_t)ks * 8 + ntb) * 64 + lane;
#pragma unroll
        for (int nt = 0; nt < 2; ++nt) {
            v8s b = bp[nt * 64];
            acc[0][nt] = __builtin_amdgcn_mfma_f32_16x16x32_bf16(a0, b, acc[0][nt], 0, 0, 0);
            acc[1][nt] = __builtin_amdgcn_mfma_f32_16x16x32_bf16(a1, b, acc[1][nt], 0, 0, 0);
        }
    }
#pragma unroll
    for (int nt = 0; nt < 2; ++nt) {
        int n = (ntb + nt) * 16 + m;
        float bv = pb[n];
#pragma unroll
        for (int mt = 0; mt < 2; ++mt)
#pragma unroll
            for (int rg = 0; rg < 4; ++rg) {
                int row = mt * 16 + quad * 4 + rg;
                size_t gi = (row0 + row) * 128 + n;
                yws[gi] = x[gi] + bv + acc[mt][nt][rg];
            }
    }
}

// ---------------------------------------------------------------------------
// Kernel 5 (MFMA): ffn = gelu(LN(y)@f1+b1)@f2+b2; out = y + ffn. (unchanged)
// ---------------------------------------------------------------------------
__global__ __launch_bounds__(256) void k_ffn(const float* __restrict__ yws,
                                             const float* __restrict__ g, const float* __restrict__ bb,
                                             const bf16* __restrict__ w1f, const float* __restrict__ b1,
                                             const bf16* __restrict__ w2f, const float* __restrict__ b2,
                                             float* __restrict__ outp) {
    __shared__ short An[32][136];
    __shared__ short Hs[32][520];
    const int t = threadIdx.x;
    const size_t row0 = (size_t)blockIdx.x * 32;
    {
        const int r = t >> 3, li = t & 7;
        const float* yr = yws + (row0 + r) * 128 + li * 16;
        float v[16];
        float s1 = 0.f, s2 = 0.f;
#pragma unroll
        for (int k4 = 0; k4 < 4; ++k4) {
            float4 vv = *(const float4*)(yr + 4 * k4);
            v[4 * k4 + 0] = vv.x; v[4 * k4 + 1] = vv.y; v[4 * k4 + 2] = vv.z; v[4 * k4 + 3] = vv.w;
            s1 += vv.x + vv.y + vv.z + vv.w;
            s2 += vv.x * vv.x + vv.y * vv.y + vv.z * vv.z + vv.w * vv.w;
        }
#pragma unroll
        for (int o = 1; o < 8; o <<= 1) { s1 += __shfl_xor(s1, o); s2 += __shfl_xor(s2, o); }
        float mu = s1 * (1.f / 128.f);
        float rs = rsqrtf(s2 * (1.f / 128.f) - mu * mu + 1e-5f);
        v8s lo, hi;
#pragma unroll
        for (int k = 0; k < 8; ++k) {
            int c = li * 16 + k;
            lo[k] = f2bs((v[k] - mu) * rs * g[c] + bb[c]);
        }
#pragma unroll
        for (int k = 0; k < 8; ++k) {
            int c = li * 16 + 8 + k;
            hi[k] = f2bs((v[8 + k] - mu) * rs * g[c] + bb[c]);
        }
        *(v8s*)&An[r][li * 16]     = lo;
        *(v8s*)&An[r][li * 16 + 8] = hi;
    }
    __syncthreads();
    const int lane = t & 63, wv = t >> 6;
    const int m = lane & 15, quad = lane >> 4;
    v4f acc1[2][8];
#pragma unroll
    for (int a = 0; a < 2; ++a)
#pragma unroll
        for (int b = 0; b < 8; ++b) acc1[a][b] = (v4f){0.f, 0.f, 0.f, 0.f};
    const int n0w = wv * 128;
#pragma unroll
    for (int ks = 0; ks < 4; ++ks) {
        v8s a0 = *(const v8s*)&An[m][ks * 32 + quad * 8];
        v8s a1 = *(const v8s*)&An[m + 16][ks * 32 + quad * 8];
        const v8s* bp = (const v8s*)w1f + ((size_t)ks * 32 + (n0w >> 4)) * 64 + lane;
#pragma unroll
        for (int nt = 0; nt < 8; ++nt) {
            v8s b = bp[nt * 64];
            acc1[0][nt] = __builtin_amdgcn_mfma_f32_16x16x32_bf16(a0, b, acc1[0][nt], 0, 0, 0);
            acc1[1][nt] = __builtin_amdgcn_mfma_f32_16x16x32_bf16(a1, b, acc1[1][nt], 0, 0, 0);
        }
    }
#pragma unroll
    for (int nt = 0; nt < 8; ++nt) {
        int n = n0w + nt * 16 + m;
        float b1v = b1[n];
#pragma unroll
        for (int mt = 0; mt < 2; ++mt)
#pragma unroll
            for (int rg = 0; rg < 4; ++rg)
                Hs[mt * 16 + quad * 4 + rg][n] = f2bs(gelu_exact(acc1[mt][nt][rg] + b1v));
    }
    __syncthreads();
    v4f acc2[2][2];
#pragma unroll
    for (int a = 0; a < 2; ++a)
#pragma unroll
        for (int b = 0; b < 2; ++b) acc2[a][b] = (v4f){0.f, 0.f, 0.f, 0.f};
    const int ntb = wv * 2;
#pragma unroll
    for (int ks = 0; ks < 16; ++ks) {
        v8s a0 = *(const v8s*)&Hs[m][ks * 32 + quad * 8];
        v8s a1 = *(const v8s*)&Hs[m + 16][ks * 32 + quad * 8];
        const v8s* bp = (const v8s*)w2f + ((size_t)ks * 8 + ntb) * 64 + lane;
#pragma unroll
        for (int nt = 0; nt < 2; ++nt) {
            v8s b = bp[nt * 64];
            acc2[0][nt] = __builtin_amdgcn_mfma_f32_16x16x32_bf16(a0, b, acc2[0][nt], 0, 0, 0);
            acc2[1][nt] = __builtin_amdgcn_mfma_f32_16x16x32_bf16(a1, b, acc2[1][nt], 0, 0, 0);
        }
    }
#pragma unroll
    for (int nt = 0; nt < 2; ++nt) {
        int n = (ntb + nt) * 16 + m;
        float b2v = b2[n];
#pragma unroll
        for (int mt = 0; mt < 2; ++mt)
#pragma unroll
            for (int rg = 0; rg < 4; ++rg) {
                int row = mt * 16 + quad * 4 + rg;
                size_t gi = (row0 + row) * 128 + n;
                outp[gi] = yws[gi] + b2v + acc2[mt][nt][rg];
            }
    }
}

extern "C" void kernel_launch(void* const* d_in, const int* in_sizes, int n_in,
                              void* d_out, int out_size, void* d_ws, size_t ws_size,
                              hipStream_t stream) {
    const float* x      = (const float*)d_in[0];
    const float* ctx    = (const float*)d_in[1];
    const float* ctxn_g = (const float*)d_in[2];
    const float* ctxn_b = (const float*)d_in[3];
    const float* ctxp_w = (const float*)d_in[4];
    const float* ctxp_b = (const float*)d_in[5];
    const float* n1_g   = (const float*)d_in[6];
    const float* n1_b   = (const float*)d_in[7];
    const float* n1v_g  = (const float*)d_in[8];
    const float* n1v_b  = (const float*)d_in[9];
    const float* q_w    = (const float*)d_in[10];
    const float* q_b    = (const float*)d_in[11];
    const float* k_w    = (const float*)d_in[12];
    const float* k_b    = (const float*)d_in[13];
    const float* v_w    = (const float*)d_in[14];
    const float* v_b    = (const float*)d_in[15];
    const float* rpb    = (const float*)d_in[16];
    const float* proj_w = (const float*)d_in[17];
    const float* proj_b = (const float*)d_in[18];
    const float* n2_g   = (const float*)d_in[19];
    const float* n2_b   = (const float*)d_in[20];
    const float* f1_w   = (const float*)d_in[21];
    const float* f1_b   = (const float*)d_in[22];
    const float* f2_w   = (const float*)d_in[23];
    const float* f2_b   = (const float*)d_in[24];
    float* out = (float*)d_out;

    char* ws = (char*)d_ws;
    bf16*  ctxp = (bf16*)(ws);                    //  8,388,608 B  (B,HW,64) bf16
    bf16*  qws  = (bf16*)(ws + 8388608);          // 16,777,216 B  (B,8,HW,16) bf16
    bf16*  kws  = (bf16*)(ws + 25165824);         // 16,777,216 B
    bf16*  vws  = (bf16*)(ws + 41943040);         // 16,777,216 B
    bf16*  ows  = (bf16*)(ws + 58720256);         // 16,777,216 B  (B,HW,128) bf16
    // yws aliases qws+kws (dead after k_attn; k_proj runs after k_attn)
    float* yws  = (float*)(ws + 8388608);         // 33,554,432 B  (B,HW,128) fp32
    char* frag = ws + 75497472;
    bf16*  w1f  = (bf16*)(frag);                  // 131,072 B
    bf16*  w2f  = (bf16*)(frag + 131072);         // 131,072 B
    bf16*  qwf  = (bf16*)(frag + 262144);         //  49,152 B
    bf16*  kwf  = (bf16*)(frag + 311296);         //  49,152 B
    bf16*  vwf  = (bf16*)(frag + 360448);         //  32,768 B
    bf16*  pwf  = (bf16*)(frag + 393216);         //  65,536 B
    // total 75,956,224 B

    k_repack<<<256, 256, 0, stream>>>(f1_w, w1f, 128, 512);
    k_repack<<<256, 256, 0, stream>>>(f2_w, w2f, 512, 128);
    k_repack<<<96,  256, 0, stream>>>(q_w,  qwf, 192, 128);
    k_repack<<<96,  256, 0, stream>>>(k_w,  kwf, 192, 128);
    k_repack<<<64,  256, 0, stream>>>(v_w,  vwf, 128, 128);
    k_repack<<<128, 256, 0, stream>>>(proj_w, pwf, 256, 128);
    k_ctx<<<1024, 256, 0, stream>>>(ctx, ctxn_g, ctxn_b, ctxp_w, ctxp_b, ctxp);
    k_qkv<<<2048, 256, 0, stream>>>(x, ctxp, n1_g, n1_b, n1v_g, n1v_b,
                                    qwf, q_b, kwf, k_b, vwf, v_b, qws, kws, vws);
    k_attn<<<2048, 256, 0, stream>>>(qws, kws, vws, rpb, ows);
    k_proj<<<2048, 256, 0, stream>>>(x, ows, pwf, proj_b, yws);
    k_ffn<<<2048, 256, 0, stream>>>(yws, n2_g, n2_b, w1f, f1_b, w2f, f2_b, out);
}

// Round 6
// 481.524 us; speedup vs baseline: 19.9869x; 1.2049x over previous
//
#include <hip/hip_runtime.h>
#include <hip/hip_bf16.h>
#include <math.h>

typedef __hip_bfloat16 bf16;
typedef float v2f __attribute__((ext_vector_type(2)));
typedef float v4f __attribute__((ext_vector_type(4)));
typedef short v8s __attribute__((ext_vector_type(8)));
typedef _Float16 v2h __attribute__((ext_vector_type(2)));

__device__ __forceinline__ float b2f(bf16 v) { return __bfloat162float(v); }
__device__ __forceinline__ float unpk_lo(unsigned u) { return __uint_as_float(u << 16); }
__device__ __forceinline__ float unpk_hi(unsigned u) { return __uint_as_float(u & 0xffff0000u); }
__device__ __forceinline__ v2f unpk2(unsigned u) {
    v2f r; r.x = __uint_as_float(u << 16); r.y = __uint_as_float(u & 0xffff0000u); return r;
}
__device__ __forceinline__ unsigned pk2(float a, float b) {
    unsigned ua = __float_as_uint(a);
    unsigned ub = __float_as_uint(b);
    ua = (ua + 0x7fffu + ((ua >> 16) & 1u)) >> 16;   // RNE to bf16
    ub = (ub + 0x7fffu + ((ub >> 16) & 1u)) >> 16;
    return ua | (ub << 16);
}
__device__ __forceinline__ short f2bs(float f) {
    unsigned u = __float_as_uint(f);
    u = (u + 0x7fffu + ((u >> 16) & 1u)) >> 16;
    return (short)u;
}
__device__ __forceinline__ v2h u2h(unsigned u) {
    union { unsigned u; v2h h; } c; c.u = u; return c.h;
}
__device__ __forceinline__ float gelu_exact(float x) {
    return 0.5f * x * (1.f + erff(x * 0.70710678118654752440f));
}

#define LOG2E 1.44269504088896340736f

// ---------------------------------------------------------------------------
// Repack a KxN fp32 weight into bf16 MFMA B-fragments for 16x16x32.
// ---------------------------------------------------------------------------
__global__ __launch_bounds__(256) void k_repack(const float* __restrict__ src,
                                                bf16* __restrict__ dst, int K, int N) {
    int idx = blockIdx.x * 256 + threadIdx.x;
    if (idx >= K * N) return;
    int k = idx / N, n = idx % N;
    int kstep = k >> 5, quad = (k & 31) >> 3, j = k & 7;
    int ntile = n >> 4, nn = n & 15;
    size_t di = ((((size_t)kstep * (N >> 4)) + ntile) * 64 + nn + (quad << 4)) * 8 + j;
    dst[di] = __float2bfloat16(src[idx]);
}

// rpb -> log2e*rpb - 8  (the -8 cancels in softmax normalization; keeps
// unnormalized f16 PV accumulation far from overflow)
__global__ __launch_bounds__(256) void k_rpb(const float* __restrict__ src,
                                             float* __restrict__ dst, int n) {
    int i = blockIdx.x * 256 + threadIdx.x;
    if (i < n) dst[i] = src[i] * LOG2E - 8.0f;
}

// ---------------------------------------------------------------------------
// Kernel 1: ctx = LN(context^T over EC=256) @ ctxp_w + ctxp_b -> (B,HW,64) bf16
// ---------------------------------------------------------------------------
__global__ __launch_bounds__(256) void k_ctx(const float* __restrict__ ctx,
                                             const float* __restrict__ g,
                                             const float* __restrict__ bb,
                                             const float* __restrict__ w,
                                             const float* __restrict__ pb,
                                             bf16* __restrict__ outp) {
    __shared__ unsigned tile[256][32];
    __shared__ float redS[8][64];
    __shared__ float redQ[8][64];
    __shared__ float s_mu[64], s_rs[64];
    const int t  = threadIdx.x;
    const int tx = t & 31;
    const int ty = t >> 5;
    const int b   = blockIdx.x >> 6;
    const int hw0 = (blockIdx.x & 63) << 6;
    const float* cbase = ctx + ((size_t)b * 256) * 4096 + hw0 + 2 * tx;
    float sa = 0.f, qa = 0.f, sb = 0.f, qb2 = 0.f;
    for (int e = ty; e < 256; e += 8) {
        float2 v = *(const float2*)(cbase + (size_t)e * 4096);
        tile[e][tx] = pk2(v.x, v.y);
        sa += v.x; qa += v.x * v.x;
        sb += v.y; qb2 += v.y * v.y;
    }
    redS[ty][2 * tx] = sa;  redS[ty][2 * tx + 1] = sb;
    redQ[ty][2 * tx] = qa;  redQ[ty][2 * tx + 1] = qb2;
    __syncthreads();
    if (t < 64) {
        float st = 0.f, qt = 0.f;
#pragma unroll
        for (int k = 0; k < 8; ++k) { st += redS[k][t]; qt += redQ[k][t]; }
        float mu = st * (1.f / 256.f);
        float var = qt * (1.f / 256.f) - mu * mu;
        s_mu[t] = mu;
        s_rs[t] = rsqrtf(var + 1e-5f);
    }
    __syncthreads();
    {
        float mu0 = s_mu[2 * tx], mu1 = s_mu[2 * tx + 1];
        float rs0 = s_rs[2 * tx], rs1 = s_rs[2 * tx + 1];
        for (int e = ty; e < 256; e += 8) {
            unsigned u = tile[e][tx];
            float ge = g[e], be = bb[e];
            float a0 = (unpk_lo(u) - mu0) * rs0 * ge + be;
            float a1 = (unpk_hi(u) - mu1) * rs1 * ge + be;
            tile[e][tx] = pk2(a0, a1);
        }
    }
    __syncthreads();
    const int tx2 = t & 63;
    const int ty2 = t >> 6;
    v2f acc[8];
#pragma unroll
    for (int q = 0; q < 8; ++q) { acc[q].x = pb[ty2 * 16 + 2 * q]; acc[q].y = pb[ty2 * 16 + 2 * q + 1]; }
    for (int e = 0; e < 256; ++e) {
        unsigned u = tile[e][tx2 >> 1];
        float a = (tx2 & 1) ? unpk_hi(u) : unpk_lo(u);
        const float4* wv = (const float4*)(w + e * 64 + ty2 * 16);
        float4 w0 = wv[0], w1 = wv[1], w2v = wv[2], w3 = wv[3];
        acc[0] += (v2f){w0.x, w0.y} * a;   acc[1] += (v2f){w0.z, w0.w} * a;
        acc[2] += (v2f){w1.x, w1.y} * a;   acc[3] += (v2f){w1.z, w1.w} * a;
        acc[4] += (v2f){w2v.x, w2v.y} * a; acc[5] += (v2f){w2v.z, w2v.w} * a;
        acc[6] += (v2f){w3.x, w3.y} * a;   acc[7] += (v2f){w3.z, w3.w} * a;
    }
    unsigned* orow = (unsigned*)(outp + ((size_t)b * 4096 + hw0 + tx2) * 64 + ty2 * 16);
    uint4 o0, o1;
    o0.x = pk2(acc[0].x, acc[0].y); o0.y = pk2(acc[1].x, acc[1].y);
    o0.z = pk2(acc[2].x, acc[2].y); o0.w = pk2(acc[3].x, acc[3].y);
    o1.x = pk2(acc[4].x, acc[4].y); o1.y = pk2(acc[5].x, acc[5].y);
    o1.z = pk2(acc[6].x, acc[6].y); o1.w = pk2(acc[7].x, acc[7].y);
    ((uint4*)orow)[0] = o0;
    ((uint4*)orow)[1] = o1;
}

// ---------------------------------------------------------------------------
// Kernel 2 (MFMA): LN(concat(x,ctx),192) -> q,k ; LN(x,128) -> v.
// q/k/v written as f16 (q folded with 0.25*log2e for exp2-softmax).
// ---------------------------------------------------------------------------
__global__ __launch_bounds__(256) void k_qkv(const float* __restrict__ x,
                                             const bf16* __restrict__ ctxp,
                                             const float* __restrict__ n1g, const float* __restrict__ n1b,
                                             const float* __restrict__ nvg, const float* __restrict__ nvb,
                                             const bf16* __restrict__ qwf, const float* __restrict__ qb,
                                             const bf16* __restrict__ kwf, const float* __restrict__ kb,
                                             const bf16* __restrict__ vwf, const float* __restrict__ vb,
                                             _Float16* __restrict__ qo, _Float16* __restrict__ ko,
                                             _Float16* __restrict__ vo) {
    __shared__ short Aqk[32][200];
    __shared__ short Av[32][136];
    const int t = threadIdx.x;
    const size_t row0 = (size_t)blockIdx.x * 32;
    {
        const int r = t >> 3, li = t & 7;
        const float* xr = x + (row0 + r) * 128 + li * 16;
        float v[16];
        float sx1 = 0.f, sx2 = 0.f;
#pragma unroll
        for (int k4 = 0; k4 < 4; ++k4) {
            float4 vv = *(const float4*)(xr + 4 * k4);
            v[4 * k4 + 0] = vv.x; v[4 * k4 + 1] = vv.y; v[4 * k4 + 2] = vv.z; v[4 * k4 + 3] = vv.w;
            sx1 += vv.x + vv.y + vv.z + vv.w;
            sx2 += vv.x * vv.x + vv.y * vv.y + vv.z * vv.z + vv.w * vv.w;
        }
        float cv[8];
        float sc1 = 0.f, sc2 = 0.f;
        {
            uint4 cu = *(const uint4*)(ctxp + (row0 + r) * 64 + li * 8);
            v2f p0 = unpk2(cu.x), p1 = unpk2(cu.y), p2 = unpk2(cu.z), p3 = unpk2(cu.w);
            cv[0] = p0.x; cv[1] = p0.y; cv[2] = p1.x; cv[3] = p1.y;
            cv[4] = p2.x; cv[5] = p2.y; cv[6] = p3.x; cv[7] = p3.y;
#pragma unroll
            for (int k = 0; k < 8; ++k) { sc1 += cv[k]; sc2 += cv[k] * cv[k]; }
        }
#pragma unroll
        for (int o = 1; o < 8; o <<= 1) {
            sx1 += __shfl_xor(sx1, o); sx2 += __shfl_xor(sx2, o);
            sc1 += __shfl_xor(sc1, o); sc2 += __shfl_xor(sc2, o);
        }
        float mu  = (sx1 + sc1) * (1.f / 192.f);
        float rs  = rsqrtf((sx2 + sc2) * (1.f / 192.f) - mu * mu + 1e-5f);
        float muv = sx1 * (1.f / 128.f);
        float rsv = rsqrtf(sx2 * (1.f / 128.f) - muv * muv + 1e-5f);
        v8s q0, q1, vv0, vv1, cc;
#pragma unroll
        for (int k = 0; k < 8; ++k) {
            int c = li * 16 + k;
            q0[k]  = f2bs((v[k] - mu) * rs * n1g[c] + n1b[c]);
            vv0[k] = f2bs((v[k] - muv) * rsv * nvg[c] + nvb[c]);
        }
#pragma unroll
        for (int k = 0; k < 8; ++k) {
            int c = li * 16 + 8 + k;
            q1[k]  = f2bs((v[8 + k] - mu) * rs * n1g[c] + n1b[c]);
            vv1[k] = f2bs((v[8 + k] - muv) * rsv * nvg[c] + nvb[c]);
        }
#pragma unroll
        for (int k = 0; k < 8; ++k) {
            int c = 128 + li * 8 + k;
            cc[k] = f2bs((cv[k] - mu) * rs * n1g[c] + n1b[c]);
        }
        *(v8s*)&Aqk[r][li * 16]     = q0;
        *(v8s*)&Aqk[r][li * 16 + 8] = q1;
        *(v8s*)&Aqk[r][128 + li * 8] = cc;
        *(v8s*)&Av[r][li * 16]     = vv0;
        *(v8s*)&Av[r][li * 16 + 8] = vv1;
    }
    __syncthreads();
    const int lane = t & 63, wv = t >> 6;
    const int m = lane & 15, quad = lane >> 4;
    const int ntb = wv * 2;
    v4f aq[2][2], ak[2][2], av[2][2];
#pragma unroll
    for (int a = 0; a < 2; ++a)
#pragma unroll
        for (int b = 0; b < 2; ++b) {
            aq[a][b] = (v4f){0.f, 0.f, 0.f, 0.f};
            ak[a][b] = (v4f){0.f, 0.f, 0.f, 0.f};
            av[a][b] = (v4f){0.f, 0.f, 0.f, 0.f};
        }
#pragma unroll
    for (int ks = 0; ks < 6; ++ks) {
        v8s a0 = *(const v8s*)&Aqk[m][ks * 32 + quad * 8];
        v8s a1 = *(const v8s*)&Aqk[m + 16][ks * 32 + quad * 8];
        const v8s* bpq = (const v8s*)qwf + ((size_t)ks * 8 + ntb) * 64 + lane;
        const v8s* bpk = (const v8s*)kwf + ((size_t)ks * 8 + ntb) * 64 + lane;
#pragma unroll
        for (int nt = 0; nt < 2; ++nt) {
            v8s bq = bpq[nt * 64];
            v8s bk = bpk[nt * 64];
            aq[0][nt] = __builtin_amdgcn_mfma_f32_16x16x32_bf16(a0, bq, aq[0][nt], 0, 0, 0);
            aq[1][nt] = __builtin_amdgcn_mfma_f32_16x16x32_bf16(a1, bq, aq[1][nt], 0, 0, 0);
            ak[0][nt] = __builtin_amdgcn_mfma_f32_16x16x32_bf16(a0, bk, ak[0][nt], 0, 0, 0);
            ak[1][nt] = __builtin_amdgcn_mfma_f32_16x16x32_bf16(a1, bk, ak[1][nt], 0, 0, 0);
        }
    }
#pragma unroll
    for (int ks = 0; ks < 4; ++ks) {
        v8s a0 = *(const v8s*)&Av[m][ks * 32 + quad * 8];
        v8s a1 = *(const v8s*)&Av[m + 16][ks * 32 + quad * 8];
        const v8s* bpv = (const v8s*)vwf + ((size_t)ks * 8 + ntb) * 64 + lane;
#pragma unroll
        for (int nt = 0; nt < 2; ++nt) {
            v8s bv = bpv[nt * 64];
            av[0][nt] = __builtin_amdgcn_mfma_f32_16x16x32_bf16(a0, bv, av[0][nt], 0, 0, 0);
            av[1][nt] = __builtin_amdgcn_mfma_f32_16x16x32_bf16(a1, bv, av[1][nt], 0, 0, 0);
        }
    }
#pragma unroll
    for (int nt = 0; nt < 2; ++nt) {
        int n = (ntb + nt) * 16 + m;
        int head = n >> 4, d = n & 15;
        float qbv = qb[n], kbv = kb[n], vbv = vb[n];
#pragma unroll
        for (int mt = 0; mt < 2; ++mt)
#pragma unroll
            for (int rg = 0; rg < 4; ++rg) {
                int rowg = (int)row0 + mt * 16 + quad * 4 + rg;
                int b = rowg >> 12, hw = rowg & 4095;
                size_t oi = (((size_t)b * 8 + head) * 4096 + hw) * 16 + d;
                qo[oi] = (_Float16)((aq[mt][nt][rg] + qbv) * (0.25f * LOG2E));
                ko[oi] = (_Float16)(ak[mt][nt][rg] + kbv);
                vo[oi] = (_Float16)(av[mt][nt][rg] + vbv);
            }
    }
}

// ---------------------------------------------------------------------------
// Kernel 3: neighborhood attention, f16 + v_dot2 + pk_fma_f16.
// ktv: k|v interleaved per column, 20-uint (80B) stride -> ds_read_b128.
// ---------------------------------------------------------------------------
__global__ __launch_bounds__(256) void k_attn(const _Float16* __restrict__ qws,
                                              const _Float16* __restrict__ kws,
                                              const _Float16* __restrict__ vws,
                                              const float* __restrict__ rpbl2,
                                              bf16* __restrict__ ows) {
    __shared__ unsigned ktv[14][64][20];   // [0..7]=k f16x16, [8..15]=v, [16..19] pad
    const int tid  = threadIdx.x;
    const int bh   = blockIdx.x >> 4;
    const int i0   = (blockIdx.x & 15) << 2;
    const int head = bh & 7;
    int start_min = i0 - 5; if (start_min < 0) start_min = 0; if (start_min > 53) start_min = 53;
    const unsigned* ku = (const unsigned*)kws;
    const unsigned* vu = (const unsigned*)vws;
    const size_t gbase = ((size_t)bh * 4096 + (size_t)start_min * 64) * 8;
    for (int idx = tid; idx < 1792; idx += 256) {
        int a = idx >> 7, rem = idx & 127, col = rem >> 1, h4 = (rem & 1) * 4;
        if (start_min + a < 64) {
            *(uint4*)&ktv[a][col][h4]     = *(const uint4*)(ku + gbase + (size_t)a * 512 + col * 8 + h4);
            *(uint4*)&ktv[a][col][8 + h4] = *(const uint4*)(vu + gbase + (size_t)a * 512 + col * 8 + h4);
        }
    }
    __syncthreads();
    const int wv = tid >> 6;
    const int j  = tid & 63;
    const int i  = i0 + wv;
    int start_i = i - 5; if (start_i < 0) start_i = 0; if (start_i > 53) start_i = 53;
    const int off = start_i - start_min;
    v2h qh[8];
    {
        const uint4* qp = (const uint4*)(qws + ((size_t)bh * 4096 + i * 64 + j) * 16);
        uint4 q0 = qp[0], q1 = qp[1];
        qh[0] = u2h(q0.x); qh[1] = u2h(q0.y); qh[2] = u2h(q0.z); qh[3] = u2h(q0.w);
        qh[4] = u2h(q1.x); qh[5] = u2h(q1.y); qh[6] = u2h(q1.z); qh[7] = u2h(q1.w);
    }
    int start_j = j - 5; if (start_j < 0) start_j = 0; if (start_j > 53) start_j = 53;
    float l = 0.f;
    v2h acc[8];
#pragma unroll
    for (int d = 0; d < 8; ++d) acc[d] = (v2h){(_Float16)0.f, (_Float16)0.f};
    const float* rpb_h = rpbl2 + head * 441 + (start_j - j + 10);
    for (int a = 0; a < 11; ++a) {
        const int r = off + a;
        const float* rb = rpb_h + (start_i + a - i + 10) * 21;
#pragma unroll
        for (int c = 0; c < 11; ++c) {
            const unsigned* cp = ktv[r][start_j + c];
            uint4 k0 = *(const uint4*)(cp);
            uint4 k1 = *(const uint4*)(cp + 4);
            uint4 v0 = *(const uint4*)(cp + 8);
            uint4 v1 = *(const uint4*)(cp + 12);
            float sa = __builtin_amdgcn_fdot2(qh[0], u2h(k0.x), rb[c], false);
            sa = __builtin_amdgcn_fdot2(qh[1], u2h(k0.y), sa, false);
            sa = __builtin_amdgcn_fdot2(qh[2], u2h(k0.z), sa, false);
            sa = __builtin_amdgcn_fdot2(qh[3], u2h(k0.w), sa, false);
            float sb = __builtin_amdgcn_fdot2(qh[4], u2h(k1.x), 0.f, false);
            sb = __builtin_amdgcn_fdot2(qh[5], u2h(k1.y), sb, false);
            sb = __builtin_amdgcn_fdot2(qh[6], u2h(k1.z), sb, false);
            sb = __builtin_amdgcn_fdot2(qh[7], u2h(k1.w), sb, false);
            float p = __builtin_amdgcn_exp2f(sa + sb);
            l += p;
            _Float16 ph = (_Float16)p;
            v2h p2 = {ph, ph};
            acc[0] += u2h(v0.x) * p2;
            acc[1] += u2h(v0.y) * p2;
            acc[2] += u2h(v0.z) * p2;
            acc[3] += u2h(v0.w) * p2;
            acc[4] += u2h(v1.x) * p2;
            acc[5] += u2h(v1.y) * p2;
            acc[6] += u2h(v1.z) * p2;
            acc[7] += u2h(v1.w) * p2;
        }
    }
    float inv = 1.f / l;
    int b = bh >> 3;
    unsigned* op = (unsigned*)ows + ((size_t)b * 4096 + i * 64 + j) * 64 + head * 8;
#pragma unroll
    for (int d2 = 0; d2 < 8; ++d2)
        op[d2] = pk2((float)acc[d2].x * inv, (float)acc[d2].y * inv);
}

// ---------------------------------------------------------------------------
// Kernel 4 (MFMA): y = x + concat(o, x) @ proj_w + proj_b -> fp32 ws.
// ---------------------------------------------------------------------------
__global__ __launch_bounds__(256) void k_proj(const float* __restrict__ x,
                                              const bf16* __restrict__ ows,
                                              const bf16* __restrict__ pwf,
                                              const float* __restrict__ pb,
                                              float* __restrict__ yws) {
    __shared__ short An[32][264];
    const int t = threadIdx.x;
    const size_t row0 = (size_t)blockIdx.x * 32;
    {
        const int r = t >> 3, li = t & 7;
        const uint4* osrc = (const uint4*)(ows + (row0 + r) * 128 + li * 16);
        uint4 o0 = osrc[0], o1 = osrc[1];
        *(uint4*)&An[r][li * 16]     = o0;
        *(uint4*)&An[r][li * 16 + 8] = o1;
        const float* xr = x + (row0 + r) * 128 + li * 16;
        v8s xa, xb;
#pragma unroll
        for (int k4 = 0; k4 < 2; ++k4) {
            float4 vv = *(const float4*)(xr + 4 * k4);
            xa[4 * k4 + 0] = f2bs(vv.x); xa[4 * k4 + 1] = f2bs(vv.y);
            xa[4 * k4 + 2] = f2bs(vv.z); xa[4 * k4 + 3] = f2bs(vv.w);
        }
#pragma unroll
        for (int k4 = 0; k4 < 2; ++k4) {
            float4 vv = *(const float4*)(xr + 8 + 4 * k4);
            xb[4 * k4 + 0] = f2bs(vv.x); xb[4 * k4 + 1] = f2bs(vv.y);
            xb[4 * k4 + 2] = f2bs(vv.z); xb[4 * k4 + 3] = f2bs(vv.w);
        }
        *(v8s*)&An[r][128 + li * 16]     = xa;
        *(v8s*)&An[r][128 + li * 16 + 8] = xb;
    }
    __syncthreads();
    const int lane = t & 63, wv = t >> 6;
    const int m = lane & 15, quad = lane >> 4;
    const int ntb = wv * 2;
    v4f acc[2][2];
#pragma unroll
    for (int a = 0; a < 2; ++a)
#pragma unroll
        for (int b = 0; b < 2; ++b) acc[a][b] = (v4f){0.f, 0.f, 0.f, 0.f};
#pragma unroll
    for (int ks = 0; ks < 8; ++ks) {
        v8s a0 = *(const v8s*)&An[m][ks * 32 + quad * 8];
        v8s a1 = *(const v8s*)&An[m + 16][ks * 32 + quad * 8];
        const v8s* bp = (const v8s*)pwf + ((size_t)ks * 8 + ntb) * 64 + lane;
#pragma unroll
        for (int nt = 0; nt < 2; ++nt) {
            v8s b = bp[nt * 64];
            acc[0][nt] = __builtin_amdgcn_mfma_f32_16x16x32_bf16(a0, b, acc[0][nt], 0, 0, 0);
            acc[1][nt] = __builtin_amdgcn_mfma_f32_16x16x32_bf16(a1, b, acc[1][nt], 0, 0, 0);
        }
    }
#pragma unroll
    for (int nt = 0; nt < 2; ++nt) {
        int n = (ntb + nt) * 16 + m;
        float bv = pb[n];
#pragma unroll
        for (int mt = 0; mt < 2; ++mt)
#pragma unroll
            for (int rg = 0; rg < 4; ++rg) {
                int row = mt * 16 + quad * 4 + rg;
                size_t gi = (row0 + row) * 128 + n;
                yws[gi] = x[gi] + bv + acc[mt][nt][rg];
            }
    }
}

// ---------------------------------------------------------------------------
// Kernel 5 (MFMA): ffn = gelu(LN(y)@f1+b1)@f2+b2; out = y + ffn.
// ---------------------------------------------------------------------------
__global__ __launch_bounds__(256) void k_ffn(const float* __restrict__ yws,
                                             const float* __restrict__ g, const float* __restrict__ bb,
                                             const bf16* __restrict__ w1f, const float* __restrict__ b1,
                                             const bf16* __restrict__ w2f, const float* __restrict__ b2,
                                             float* __restrict__ outp) {
    __shared__ short An[32][136];
    __shared__ short Hs[32][520];
    const int t = threadIdx.x;
    const size_t row0 = (size_t)blockIdx.x * 32;
    {
        const int r = t >> 3, li = t & 7;
        const float* yr = yws + (row0 + r) * 128 + li * 16;
        float v[16];
        float s1 = 0.f, s2 = 0.f;
#pragma unroll
        for (int k4 = 0; k4 < 4; ++k4) {
            float4 vv = *(const float4*)(yr + 4 * k4);
            v[4 * k4 + 0] = vv.x; v[4 * k4 + 1] = vv.y; v[4 * k4 + 2] = vv.z; v[4 * k4 + 3] = vv.w;
            s1 += vv.x + vv.y + vv.z + vv.w;
            s2 += vv.x * vv.x + vv.y * vv.y + vv.z * vv.z + vv.w * vv.w;
        }
#pragma unroll
        for (int o = 1; o < 8; o <<= 1) { s1 += __shfl_xor(s1, o); s2 += __shfl_xor(s2, o); }
        float mu = s1 * (1.f / 128.f);
        float rs = rsqrtf(s2 * (1.f / 128.f) - mu * mu + 1e-5f);
        v8s lo, hi;
#pragma unroll
        for (int k = 0; k < 8; ++k) {
            int c = li * 16 + k;
            lo[k] = f2bs((v[k] - mu) * rs * g[c] + bb[c]);
        }
#pragma unroll
        for (int k = 0; k < 8; ++k) {
            int c = li * 16 + 8 + k;
            hi[k] = f2bs((v[8 + k] - mu) * rs * g[c] + bb[c]);
        }
        *(v8s*)&An[r][li * 16]     = lo;
        *(v8s*)&An[r][li * 16 + 8] = hi;
    }
    __syncthreads();
    const int lane = t & 63, wv = t >> 6;
    const int m = lane & 15, quad = lane >> 4;
    v4f acc1[2][8];
#pragma unroll
    for (int a = 0; a < 2; ++a)
#pragma unroll
        for (int b = 0; b < 8; ++b) acc1[a][b] = (v4f){0.f, 0.f, 0.f, 0.f};
    const int n0w = wv * 128;
#pragma unroll
    for (int ks = 0; ks < 4; ++ks) {
        v8s a0 = *(const v8s*)&An[m][ks * 32 + quad * 8];
        v8s a1 = *(const v8s*)&An[m + 16][ks * 32 + quad * 8];
        const v8s* bp = (const v8s*)w1f + ((size_t)ks * 32 + (n0w >> 4)) * 64 + lane;
#pragma unroll
        for (int nt = 0; nt < 8; ++nt) {
            v8s b = bp[nt * 64];
            acc1[0][nt] = __builtin_amdgcn_mfma_f32_16x16x32_bf16(a0, b, acc1[0][nt], 0, 0, 0);
            acc1[1][nt] = __builtin_amdgcn_mfma_f32_16x16x32_bf16(a1, b, acc1[1][nt], 0, 0, 0);
        }
    }
#pragma unroll
    for (int nt = 0; nt < 8; ++nt) {
        int n = n0w + nt * 16 + m;
        float b1v = b1[n];
#pragma unroll
        for (int mt = 0; mt < 2; ++mt)
#pragma unroll
            for (int rg = 0; rg < 4; ++rg)
                Hs[mt * 16 + quad * 4 + rg][n] = f2bs(gelu_exact(acc1[mt][nt][rg] + b1v));
    }
    __syncthreads();
    v4f acc2[2][2];
#pragma unroll
    for (int a = 0; a < 2; ++a)
#pragma unroll
        for (int b = 0; b < 2; ++b) acc2[a][b] = (v4f){0.f, 0.f, 0.f, 0.f};
    const int ntb = wv * 2;
#pragma unroll
    for (int ks = 0; ks < 16; ++ks) {
        v8s a0 = *(const v8s*)&Hs[m][ks * 32 + quad * 8];
        v8s a1 = *(const v8s*)&Hs[m + 16][ks * 32 + quad * 8];
        const v8s* bp = (const v8s*)w2f + ((size_t)ks * 8 + ntb) * 64 + lane;
#pragma unroll
        for (int nt = 0; nt < 2; ++nt) {
            v8s b = bp[nt * 64];
            acc2[0][nt] = __builtin_amdgcn_mfma_f32_16x16x32_bf16(a0, b, acc2[0][nt], 0, 0, 0);
            acc2[1][nt] = __builtin_amdgcn_mfma_f32_16x16x32_bf16(a1, b, acc2[1][nt], 0, 0, 0);
        }
    }
#pragma unroll
    for (int nt = 0; nt < 2; ++nt) {
        int n = (ntb + nt) * 16 + m;
        float b2v = b2[n];
#pragma unroll
        for (int mt = 0; mt < 2; ++mt)
#pragma unroll
            for (int rg = 0; rg < 4; ++rg) {
                int row = mt * 16 + quad * 4 + rg;
                size_t gi = (row0 + row) * 128 + n;
                outp[gi] = yws[gi] + b2v + acc2[mt][nt][rg];
            }
    }
}

extern "C" void kernel_launch(void* const* d_in, const int* in_sizes, int n_in,
                              void* d_out, int out_size, void* d_ws, size_t ws_size,
                              hipStream_t stream) {
    const float* x      = (const float*)d_in[0];
    const float* ctx    = (const float*)d_in[1];
    const float* ctxn_g = (const float*)d_in[2];
    const float* ctxn_b = (const float*)d_in[3];
    const float* ctxp_w = (const float*)d_in[4];
    const float* ctxp_b = (const float*)d_in[5];
    const float* n1_g   = (const float*)d_in[6];
    const float* n1_b   = (const float*)d_in[7];
    const float* n1v_g  = (const float*)d_in[8];
    const float* n1v_b  = (const float*)d_in[9];
    const float* q_w    = (const float*)d_in[10];
    const float* q_b    = (const float*)d_in[11];
    const float* k_w    = (const float*)d_in[12];
    const float* k_b    = (const float*)d_in[13];
    const float* v_w    = (const float*)d_in[14];
    const float* v_b    = (const float*)d_in[15];
    const float* rpb    = (const float*)d_in[16];
    const float* proj_w = (const float*)d_in[17];
    const float* proj_b = (const float*)d_in[18];
    const float* n2_g   = (const float*)d_in[19];
    const float* n2_b   = (const float*)d_in[20];
    const float* f1_w   = (const float*)d_in[21];
    const float* f1_b   = (const float*)d_in[22];
    const float* f2_w   = (const float*)d_in[23];
    const float* f2_b   = (const float*)d_in[24];
    float* out = (float*)d_out;

    char* ws = (char*)d_ws;
    bf16*      ctxp = (bf16*)(ws);                 //  8,388,608 B  (B,HW,64) bf16
    _Float16*  qws  = (_Float16*)(ws + 8388608);   // 16,777,216 B  (B,8,HW,16) f16
    _Float16*  kws  = (_Float16*)(ws + 25165824);  // 16,777,216 B
    _Float16*  vws  = (_Float16*)(ws + 41943040);  // 16,777,216 B
    bf16*      ows  = (bf16*)(ws + 58720256);      // 16,777,216 B  (B,HW,128) bf16
    float*     yws  = (float*)(ws + 8388608);      // aliases qws+kws (dead after attn)
    char* frag = ws + 75497472;
    bf16*  w1f  = (bf16*)(frag);                   // 131,072 B
    bf16*  w2f  = (bf16*)(frag + 131072);          // 131,072 B
    bf16*  qwf  = (bf16*)(frag + 262144);          //  49,152 B
    bf16*  kwf  = (bf16*)(frag + 311296);          //  49,152 B
    bf16*  vwf  = (bf16*)(frag + 360448);          //  32,768 B
    bf16*  pwf  = (bf16*)(frag + 393216);          //  65,536 B
    float* rpl2 = (float*)(frag + 458752);         //  14,112 B (8*441 fp32)

    k_repack<<<256, 256, 0, stream>>>(f1_w, w1f, 128, 512);
    k_repack<<<256, 256, 0, stream>>>(f2_w, w2f, 512, 128);
    k_repack<<<96,  256, 0, stream>>>(q_w,  qwf, 192, 128);
    k_repack<<<96,  256, 0, stream>>>(k_w,  kwf, 192, 128);
    k_repack<<<64,  256, 0, stream>>>(v_w,  vwf, 128, 128);
    k_repack<<<128, 256, 0, stream>>>(proj_w, pwf, 256, 128);
    k_rpb<<<14, 256, 0, stream>>>(rpb, rpl2, 8 * 441);
    k_ctx<<<1024, 256, 0, stream>>>(ctx, ctxn_g, ctxn_b, ctxp_w, ctxp_b, ctxp);
    k_qkv<<<2048, 256, 0, stream>>>(x, ctxp, n1_g, n1_b, n1v_g, n1v_b,
                                    qwf, q_b, kwf, k_b, vwf, v_b, qws, kws, vws);
    k_attn<<<2048, 256, 0, stream>>>(qws, kws, vws, rpl2, ows);
    k_proj<<<2048, 256, 0, stream>>>(x, ows, pwf, proj_b, yws);
    k_ffn<<<2048, 256, 0, stream>>>(yws, n2_g, n2_b, w1f, f1_b, w2f, f2_b, out);
}